// Round 18
// baseline (278.126 us; speedup 1.0000x reference)
//
#include <hip/hip_runtime.h>
#include <hip/hip_bf16.h>

#define B_    32
#define CIN   64
#define HW    56
#define COUT  128
#define M_    256
#define P_    576
#define L_    3136
#define N_    100352

typedef __hip_bfloat16 bf16;
typedef unsigned short u16;
typedef __attribute__((ext_vector_type(8))) short bf16x8;
typedef __attribute__((ext_vector_type(8))) unsigned short u16x8;
typedef __attribute__((ext_vector_type(4))) float f32x4;

__device__ __forceinline__ float bits2f(u16 u){ return __uint_as_float(((unsigned)u) << 16); }
__device__ __forceinline__ u16 f2bf(float f){
  bf16 h = __float2bfloat16(f);
  return *(u16*)&h;
}

// ---- K0: fragment-major operand layouts + b2 (r16 version, standard p) -----
__global__ __launch_bounds__(256) void k0_prep(const float* __restrict__ C,
                                               const float* __restrict__ W,
                                               u16* __restrict__ CbP, u16* __restrict__ CtP,
                                               float* __restrict__ b2v, u16* __restrict__ WbP){
  __shared__ float red[4];
  const int t = threadIdx.x;
  const int bid = blockIdx.x;
  if (bid < M_){
    const int m = bid;
    float s = 0.f;
    for (int p = t; p < P_; p += 256){
      float vr = bits2f(f2bf(C[(size_t)m*P_ + p]));
      s += vr*vr;
    }
    #pragma unroll
    for (int off = 32; off >= 1; off >>= 1) s += __shfl_xor(s, off);
    if ((t & 63) == 0) red[t >> 6] = s;
    __syncthreads();
    if (t == 0) b2v[m] = red[0] + red[1] + red[2] + red[3];
  } else if (bid < M_ + 72){
    const int u = (bid - M_)*256 + t;
    const int f = u >> 6, lane = u & 63;
    const int g = lane >> 4, lr = lane & 15;
    const int k = f % 18, fj = f / 18;
    const int j = fj & 3, wvq = fj >> 2;
    const int m = wvq*64 + j*16 + lr;
    const int idx = k*4 + g;
    const int o = idx & 7, rr = idx >> 3;
    u16x8 o8;
    #pragma unroll
    for (int c = 0; c < 8; ++c) o8[c] = f2bf(C[(size_t)m*P_ + (o*8 + c)*9 + rr]);
    *(u16x8*)&CbP[(size_t)u*8] = o8;
  } else if (bid < M_ + 144){
    const int u = (bid - M_ - 72)*256 + t;
    const int f = u >> 6, lane = u & 63;
    const int g = lane >> 4, lr = lane & 15;
    const int mc = f & 7, fj = f >> 3;
    const int j = fj % 9, q = fj / 9;
    const int p = q*144 + j*16 + lr;
    const int m = mc*32 + g*8;
    u16x8 o8;
    #pragma unroll
    for (int c = 0; c < 8; ++c) o8[c] = f2bf(C[(size_t)(m + c)*P_ + p]);
    *(u16x8*)&CtP[(size_t)u*8] = o8;
  } else {
    const int u = (bid - M_ - 144)*256 + t;
    const int f = u >> 6, lane = u & 63;
    const int g = lane >> 4, lr = lane & 15;
    const int k = f % 18, fi = f / 18;
    const int i = fi & 3, wn = fi >> 2;
    const int co = wn*64 + i*16 + lr;
    const int q = k*32 + g*8;
    u16x8 o8;
    #pragma unroll
    for (int c = 0; c < 8; ++c) o8[c] = f2bf(W[(size_t)co*P_ + q + c]);
    *(u16x8*)&WbP[(size_t)u*8] = o8;
  }
}

// ---- K123: fused unfold+assign+transform. 512 threads, 8 waves. ------------
// wv = ih*4+mq. Standard-p F layout (raw-reshape invariant). setprio on MFMA.
__global__ __launch_bounds__(512, 4) void k123(const float* __restrict__ x,
    const u16* __restrict__ CbP, const u16* __restrict__ CtP,
    const float* __restrict__ b2v, const float* __restrict__ temp_p,
    u16* __restrict__ F){
  __shared__ __align__(16) char lds[76288];
  u16*   xt2 = (u16*)lds;                 // 256 spat x 72 u16 = 36864 B
  char*  Bz  = lds + 36864;               // 37888 B overlay: Sl / Fl
  u16*   Sl  = (u16*)Bz;                  // 64 x 264 u16 = 33792 B
  u16*   Fl  = (u16*)Bz;                  // 64 x 296 u16 = 37888 B
  float* a2l = (float*)(lds + 74752);     // 2 x 64 f (partials by ih)
  float* red = (float*)(lds + 75264);     // 256 f

  const int t = threadIdx.x;
  const int lane = t & 63;
  const int wv = t >> 6;                  // 0..7
  const int ih = wv >> 2;
  const int mq = wv & 3;
  const int g  = lane >> 4;
  const int lr = lane & 15;
  const int blk = blockIdx.x;
  const int n0 = blk * 64;
  const int b  = n0 / L_;
  const int l0 = n0 - b * L_;
  const int h0 = l0 / 56;
  const float temp = *temp_p;

  // ---- stage x window transposed: xt2[spat=ry*64+wc][swz(ch)] ----
  const float* xb = x + (size_t)b * CIN * L_;
  {
    const int wc = t & 63;
    const int ix = wc - 1;
    #pragma unroll 4
    for (int iter = 0; iter < 32; ++iter){
      const int cw = (t >> 6) + iter*8;    // 0..255
      const int c  = cw & 63;
      const int ry = cw >> 6;
      const int iy = h0 - 1 + ry;
      float v = 0.f;
      if ((unsigned)iy < 56u && (unsigned)ix < 56u)
        v = xb[(size_t)c*L_ + iy*56 + ix];
      const int spat = ry*64 + wc;
      xt2[spat*72 + (((c>>3) + 2*spat) & 7)*8 + (c & 7)] = f2bf(v);
    }
  }
  __syncthreads();

  // ---- a2 partials: row = mq*16+lr; ih splits the 18 z-steps ----
  {
    const int l_  = l0 + mq*16 + lr;
    const int hwB = (l_/56 - h0)*64 + (l_ - (l_/56)*56);
    float s2 = 0.f;
    #pragma unroll
    for (int z = 0; z < 9; ++z){
      const int uu = (ih*9 + z)*4 + g;
      const int rr = uu >> 3, o = uu & 7;
      const int di = (rr >= 3) + (rr >= 6);
      const int spat = hwB + di*64 + (rr - di*3);
      u16x8 v8 = *(const u16x8*)&xt2[spat*72 + ((o + 2*spat) & 7)*8];
      #pragma unroll
      for (int c = 0; c < 8; ++c){
        const float vr = bits2f(v8[c]);
        s2 = fmaf(vr, vr, s2);
      }
    }
    s2 += __shfl_xor(s2, 16);
    s2 += __shfl_xor(s2, 32);
    if (g == 0) a2l[ih*64 + mq*16 + lr] = s2;
  }
  __syncthreads();               // a2l visible

  // ================= phase 1: G = A * Cb^T (no barriers) =================
  int hw2[2];
  #pragma unroll
  for (int i = 0; i < 2; ++i){
    const int li = l0 + ih*32 + i*16 + lr;
    const int hi = li / 56;
    hw2[i] = (hi - h0)*64 + (li - hi*56);
  }

  f32x4 acc[2][4];
  #pragma unroll
  for (int i = 0; i < 2; ++i)
    #pragma unroll
    for (int j = 0; j < 4; ++j) acc[i][j] = (f32x4){0.f,0.f,0.f,0.f};

  #pragma unroll
  for (int kk = 0; kk < 18; ++kk){
    const int idx = kk*4 + g;
    const int rr = idx >> 3, o = idx & 7;
    const int di = (rr >= 3) + (rr >= 6);
    const int doff = di*64 + (rr - di*3);
    bf16x8 af[2], bb[4];
    #pragma unroll
    for (int i = 0; i < 2; ++i){
      const int spat = hw2[i] + doff;
      af[i] = *(const bf16x8*)&xt2[spat*72 + ((o + 2*spat) & 7)*8];
    }
    #pragma unroll
    for (int j = 0; j < 4; ++j)
      bb[j] = *(const bf16x8*)(CbP + (((size_t)(mq*4 + j)*18 + kk)*64 + lane)*8);
    __builtin_amdgcn_s_setprio(1);
    #pragma unroll
    for (int i = 0; i < 2; ++i)
      #pragma unroll
      for (int j = 0; j < 4; ++j)
        acc[i][j] = __builtin_amdgcn_mfma_f32_16x16x32_bf16(af[i], bb[j], acc[i][j], 0, 0, 0);
    __builtin_amdgcn_s_setprio(0);
  }

  // ---- softmax over all 256 m (rows split by ih, cols by mq) ----
  float a2r[2][4], b2r[4];
  #pragma unroll
  for (int i = 0; i < 2; ++i)
    #pragma unroll
    for (int r = 0; r < 4; ++r){
      const int row = ih*32 + i*16 + g*4 + r;
      a2r[i][r] = a2l[row] + a2l[64 + row];
    }
  #pragma unroll
  for (int j = 0; j < 4; ++j) b2r[j] = b2v[mq*64 + j*16 + lr];

  float rmax[2][4];
  #pragma unroll
  for (int i = 0; i < 2; ++i)
    #pragma unroll
    for (int r = 0; r < 4; ++r) rmax[i][r] = -3.4e38f;

  #pragma unroll
  for (int i = 0; i < 2; ++i)
    #pragma unroll
    for (int j = 0; j < 4; ++j)
      #pragma unroll
      for (int r = 0; r < 4; ++r){
        float d2 = fmaxf(a2r[i][r] + b2r[j] - 2.f*acc[i][j][r], 1e-12f);
        float lg = -temp * sqrtf(d2);
        acc[i][j][r] = lg;
        rmax[i][r] = fmaxf(rmax[i][r], lg);
      }
  #pragma unroll
  for (int i = 0; i < 2; ++i)
    #pragma unroll
    for (int r = 0; r < 4; ++r){
      float v = rmax[i][r];
      v = fmaxf(v, __shfl_xor(v, 1));
      v = fmaxf(v, __shfl_xor(v, 2));
      v = fmaxf(v, __shfl_xor(v, 4));
      v = fmaxf(v, __shfl_xor(v, 8));
      rmax[i][r] = v;
    }
  __syncthreads();
  if (lr == 0){
    #pragma unroll
    for (int i = 0; i < 2; ++i)
      #pragma unroll
      for (int r = 0; r < 4; ++r)
        red[mq*64 + ih*32 + i*16 + g*4 + r] = rmax[i][r];
  }
  __syncthreads();
  #pragma unroll
  for (int i = 0; i < 2; ++i)
    #pragma unroll
    for (int r = 0; r < 4; ++r){
      const int row = ih*32 + i*16 + g*4 + r;
      rmax[i][r] = fmaxf(fmaxf(red[row], red[64+row]), fmaxf(red[128+row], red[192+row]));
    }
  float rsum[2][4];
  #pragma unroll
  for (int i = 0; i < 2; ++i)
    #pragma unroll
    for (int r = 0; r < 4; ++r) rsum[i][r] = 0.f;
  #pragma unroll
  for (int i = 0; i < 2; ++i)
    #pragma unroll
    for (int j = 0; j < 4; ++j)
      #pragma unroll
      for (int r = 0; r < 4; ++r){
        float pe = __expf(acc[i][j][r] - rmax[i][r]);
        acc[i][j][r] = pe;
        rsum[i][r] += pe;
      }
  #pragma unroll
  for (int i = 0; i < 2; ++i)
    #pragma unroll
    for (int r = 0; r < 4; ++r){
      float v = rsum[i][r];
      v += __shfl_xor(v, 1);
      v += __shfl_xor(v, 2);
      v += __shfl_xor(v, 4);
      v += __shfl_xor(v, 8);
      rsum[i][r] = v;
    }
  __syncthreads();
  if (lr == 0){
    #pragma unroll
    for (int i = 0; i < 2; ++i)
      #pragma unroll
      for (int r = 0; r < 4; ++r)
        red[mq*64 + ih*32 + i*16 + g*4 + r] = rsum[i][r];
  }
  __syncthreads();
  #pragma unroll
  for (int i = 0; i < 2; ++i)
    #pragma unroll
    for (int r = 0; r < 4; ++r){
      const int row = ih*32 + i*16 + g*4 + r;
      const float invr = 1.f / (red[row] + red[64+row] + red[128+row] + red[192+row]);
      #pragma unroll
      for (int j = 0; j < 4; ++j)
        Sl[(size_t)row*264 + mq*64 + j*16 + lr] = f2bf(acc[i][j][r] * invr);
    }
  __syncthreads();                 // Sl visible

  // ========== phase 2: T = Sl * Ct (no barriers, batch frag loads) ==========
  f32x4 acc2[2][9];
  #pragma unroll
  for (int i = 0; i < 2; ++i)
    #pragma unroll
    for (int j = 0; j < 9; ++j) acc2[i][j] = (f32x4){0.f,0.f,0.f,0.f};

  for (int mc = 0; mc < 8; ++mc){
    bf16x8 af2[2], bb2[9];
    #pragma unroll
    for (int i = 0; i < 2; ++i)
      af2[i] = *(const bf16x8*)&Sl[(size_t)(ih*32 + i*16 + lr)*264 + mc*32 + g*8];
    #pragma unroll
    for (int j = 0; j < 9; ++j)
      bb2[j] = *(const bf16x8*)(CtP + (((size_t)(mq*9 + j)*8 + mc)*64 + lane)*8);
    __builtin_amdgcn_s_setprio(1);
    #pragma unroll
    for (int j = 0; j < 9; ++j)
      #pragma unroll
      for (int i = 0; i < 2; ++i)
        acc2[i][j] = __builtin_amdgcn_mfma_f32_16x16x32_bf16(af2[i], bb2[j], acc2[i][j], 0, 0, 0);
    __builtin_amdgcn_s_setprio(0);
  }

  // ---- F write: two 288-p halves; skip term re-gathered from xt2 ----------
  const float inv = 1.f / (temp + 1.f);
  const float tscale = temp * inv;
  #pragma unroll
  for (int hh = 0; hh < 2; ++hh){
    __syncthreads();               // Fl region free
    if ((mq >> 1) == hh){
      const int pbase = (mq & 1) * 144;
      #pragma unroll
      for (int i = 0; i < 2; ++i)
        #pragma unroll
        for (int j = 0; j < 9; ++j)
          #pragma unroll
          for (int r = 0; r < 4; ++r)
            Fl[(ih*32 + i*16 + g*4 + r)*296 + pbase + j*16 + lr] = f2bf(acc2[i][j][r] * tscale);
    }
    __syncthreads();
    for (int v = t; v < 2304; v += 512){
      const int row = v / 36, col = (v - row*36) * 8;
      u16x8 tv = *(const u16x8*)&Fl[row*296 + col];
      const int p0 = hh*288 + col;
      int ch2 = p0 / 9;
      int rr2 = p0 - ch2*9;
      const int l2 = l0 + row;
      const int h2 = l2 / 56;
      const int hb2 = (h2 - h0)*64 + (l2 - h2*56);
      u16x8 o;
      #pragma unroll
      for (int c2 = 0; c2 < 8; ++c2){
        const int di2 = (rr2 >= 3) + (rr2 >= 6);
        const int spat = hb2 + di2*64 + (rr2 - di2*3);
        const u16 av_ = xt2[spat*72 + (((ch2>>3) + 2*spat) & 7)*8 + (ch2 & 7)];
        o[c2] = f2bf(bits2f(tv[c2]) + bits2f(av_) * inv);
        const bool w9 = (rr2 == 8);
        rr2 = w9 ? 0 : rr2 + 1;
        ch2 += w9 ? 1 : 0;
      }
      *(u16x8*)(F + (size_t)(n0 + row)*P_ + hh*288 + col) = o;
    }
  }
}

// ---- K4: MFMA GEMM out = WbP * F (+bias), mask fused into F staging --------
__global__ __launch_bounds__(256) void k4_conv(const u16* __restrict__ F,
    const u16* __restrict__ WbP, const float* __restrict__ bias,
    float* __restrict__ out){
  __shared__ short Fl[128*40];
  const int t = threadIdx.x;
  const int lane = t & 63;
  const int w = t >> 6;
  const int wn = w >> 1;
  const int ws = w & 1;
  const int g  = lane >> 4;
  const int lr = lane & 15;
  const int b  = blockIdx.y;
  const int s0 = blockIdx.x * 128;
  const u16* Fb = F + (size_t)b * ((size_t)P_ * L_);

  f32x4 acc[4][4];
  #pragma unroll
  for (int i = 0; i < 4; ++i)
    #pragma unroll
    for (int j = 0; j < 4; ++j) acc[i][j] = (f32x4){0.f,0.f,0.f,0.f};

  for (int step = 0; step < 18; ++step){
    const int q0 = step * 32;
    __syncthreads();
    #pragma unroll
    for (int e = 0; e < 2; ++e){
      const int c = t + e*256;
      const int ql = c & 31, sch = c >> 5;
      const int q  = q0 + ql;
      const int sbase = s0 + sch*8;
      const int scl = (sbase < L_ - 8) ? sbase : (L_ - 8);
      u16x8 v = *(const u16x8*)(Fb + (size_t)q*L_ + scl);
      const int q3 = q/3;
      const bool kx0 = (q - q3*3) == 0;
      const bool ky0 = (q3 % 3) == 0;
      const int r0 = sbase % 56;
      #pragma unroll
      for (int u = 0; u < 8; ++u){
        const bool m0 = ky0 && (sbase + u) < 56;
        const bool m1 = kx0 && ((r0 + u) == 0 || (r0 + u) == 56);
        Fl[(sch*8 + u)*40 + ql] = (m0 || m1) ? (short)0 : (short)v[u];
      }
    }
    __syncthreads();
    bf16x8 af[4], bb[4];
    #pragma unroll
    for (int i = 0; i < 4; ++i)
      af[i] = *(const bf16x8*)(WbP + (((size_t)(wn*4 + i)*18 + step)*64 + lane)*8);
    #pragma unroll
    for (int j = 0; j < 4; ++j)
      bb[j] = *(const bf16x8*)&Fl[(ws*64 + j*16 + lr)*40 + g*8];
    __builtin_amdgcn_s_setprio(1);
    #pragma unroll
    for (int i = 0; i < 4; ++i)
      #pragma unroll
      for (int j = 0; j < 4; ++j)
        acc[i][j] = __builtin_amdgcn_mfma_f32_16x16x32_bf16(af[i], bb[j], acc[i][j], 0, 0, 0);
    __builtin_amdgcn_s_setprio(0);
  }

  #pragma unroll
  for (int i = 0; i < 4; ++i)
    #pragma unroll
    for (int r = 0; r < 4; ++r){
      const int co = wn*64 + i*16 + g*4 + r;
      const float bv = bias[co];
      #pragma unroll
      for (int j = 0; j < 4; ++j){
        const int s = s0 + ws*64 + j*16 + lr;
        if (s < L_) out[((size_t)b*COUT + co)*L_ + s] = acc[i][j][r] + bv;
      }
    }
}

extern "C" void kernel_launch(void* const* d_in, const int* in_sizes, int n_in,
                              void* d_out, int out_size, void* d_ws, size_t ws_size,
                              hipStream_t stream){
  const float* x      = (const float*)d_in[0];
  const float* weight = (const float*)d_in[1];
  const float* bias   = (const float*)d_in[2];
  const float* cc     = (const float*)d_in[3];
  const float* temp_p = (const float*)d_in[4];
  float* out = (float*)d_out;

  char* ws = (char*)d_ws;
  u16*   F   = (u16*)(ws);                 // 115,605,504 B (standard [n][p])
  float* b2v = (float*)(ws + 115605504);   //       1,024 B
  u16*   CbP = (u16*)(ws + 115606528);     //     294,912 B
  u16*   CtP = (u16*)(ws + 115901440);     //     294,912 B
  u16*   WbP = (u16*)(ws + 116196352);     //     147,456 B

  k0_prep <<<436,          256, 0, stream>>>(cc, weight, CbP, CtP, b2v, WbP);
  k123    <<<N_/64,        512, 0, stream>>>(x, CbP, CtP, b2v, temp_p, F);
  k4_conv <<<dim3(25, B_), 256, 0, stream>>>(F, WbP, bias, out);
}

// Round 19
// 254.553 us; speedup vs baseline: 1.0926x; 1.0926x over previous
//
#include <hip/hip_runtime.h>
#include <hip/hip_bf16.h>

#define B_    32
#define CIN   64
#define HW    56
#define COUT  128
#define M_    256
#define P_    576
#define L_    3136
#define N_    100352

typedef __hip_bfloat16 bf16;
typedef unsigned short u16;
typedef __attribute__((ext_vector_type(8))) short bf16x8;
typedef __attribute__((ext_vector_type(8))) unsigned short u16x8;
typedef __attribute__((ext_vector_type(4))) float f32x4;

__device__ __forceinline__ float bits2f(u16 u){ return __uint_as_float(((unsigned)u) << 16); }
__device__ __forceinline__ u16 f2bf(float f){
  bf16 h = __float2bfloat16(f);
  return *(u16*)&h;
}

// ---- K0: fragment-major operand layouts + b2 -------------------------------
__global__ __launch_bounds__(256) void k0_prep(const float* __restrict__ C,
                                               const float* __restrict__ W,
                                               u16* __restrict__ CbP, u16* __restrict__ CtP,
                                               float* __restrict__ b2v, u16* __restrict__ WbP){
  __shared__ float red[4];
  const int t = threadIdx.x;
  const int bid = blockIdx.x;
  if (bid < M_){
    const int m = bid;
    float s = 0.f;
    for (int p = t; p < P_; p += 256){
      float vr = bits2f(f2bf(C[(size_t)m*P_ + p]));
      s += vr*vr;
    }
    #pragma unroll
    for (int off = 32; off >= 1; off >>= 1) s += __shfl_xor(s, off);
    if ((t & 63) == 0) red[t >> 6] = s;
    __syncthreads();
    if (t == 0) b2v[m] = red[0] + red[1] + red[2] + red[3];
  } else if (bid < M_ + 72){
    const int u = (bid - M_)*256 + t;
    const int f = u >> 6, lane = u & 63;
    const int g = lane >> 4, lr = lane & 15;
    const int k = f % 18, fj = f / 18;
    const int j = fj & 3, wvq = fj >> 2;
    const int m = wvq*64 + j*16 + lr;
    const int idx = k*4 + g;
    const int o = idx & 7, rr = idx >> 3;
    u16x8 o8;
    #pragma unroll
    for (int c = 0; c < 8; ++c) o8[c] = f2bf(C[(size_t)m*P_ + (o*8 + c)*9 + rr]);
    *(u16x8*)&CbP[(size_t)u*8] = o8;
  } else if (bid < M_ + 144){
    const int u = (bid - M_ - 72)*256 + t;
    const int f = u >> 6, lane = u & 63;
    const int g = lane >> 4, lr = lane & 15;
    const int mc = f & 7, fj = f >> 3;
    const int j = fj % 9, q = fj / 9;
    const int p = q*144 + j*16 + lr;
    const int m = mc*32 + g*8;
    u16x8 o8;
    #pragma unroll
    for (int c = 0; c < 8; ++c) o8[c] = f2bf(C[(size_t)(m + c)*P_ + p]);
    *(u16x8*)&CtP[(size_t)u*8] = o8;
  } else {
    const int u = (bid - M_ - 144)*256 + t;
    const int f = u >> 6, lane = u & 63;
    const int g = lane >> 4, lr = lane & 15;
    const int k = f % 18, fi = f / 18;
    const int i = fi & 3, wn = fi >> 2;
    const int co = wn*64 + i*16 + lr;
    const int q = k*32 + g*8;
    u16x8 o8;
    #pragma unroll
    for (int c = 0; c < 8; ++c) o8[c] = f2bf(W[(size_t)co*P_ + q + c]);
    *(u16x8*)&WbP[(size_t)u*8] = o8;
  }
}

// ---- K123: fused unfold+assign+transform. 512 threads, 8 waves. ------------
// wv = ih*4+mq: ih = row-half (32 rows), mq = m/p-quarter.
__global__ __launch_bounds__(512, 4) void k123(const float* __restrict__ x,
    const u16* __restrict__ CbP, const u16* __restrict__ CtP,
    const float* __restrict__ b2v, const float* __restrict__ temp_p,
    u16* __restrict__ F){
  __shared__ __align__(16) char lds[76288];
  u16*   xt2 = (u16*)lds;                 // 256 spat x 72 u16 = 36864 B
  char*  Bz  = lds + 36864;               // 37888 B overlay: Sl / Fl
  u16*   Sl  = (u16*)Bz;                  // 64 x 264 u16 = 33792 B
  u16*   Fl  = (u16*)Bz;                  // 64 x 296 u16 = 37888 B
  float* a2l = (float*)(lds + 74752);     // 2 x 64 f (partials by ih)
  float* red = (float*)(lds + 75264);     // 256 f

  const int t = threadIdx.x;
  const int lane = t & 63;
  const int wv = t >> 6;                  // 0..7
  const int ih = wv >> 2;                 // row half
  const int mq = wv & 3;                  // m/p quarter
  const int g  = lane >> 4;
  const int lr = lane & 15;
  const int blk = blockIdx.x;
  const int n0 = blk * 64;
  const int b  = n0 / L_;
  const int l0 = n0 - b * L_;
  const int h0 = l0 / 56;
  const float temp = *temp_p;

  // ---- stage x window transposed: xt2[spat=ry*64+wc][swz(ch)] ----
  const float* xb = x + (size_t)b * CIN * L_;
  {
    const int wc = t & 63;
    const int ix = wc - 1;
    #pragma unroll 4
    for (int iter = 0; iter < 32; ++iter){
      const int cw = (t >> 6) + iter*8;    // 0..255
      const int c  = cw & 63;
      const int ry = cw >> 6;
      const int iy = h0 - 1 + ry;
      float v = 0.f;
      if ((unsigned)iy < 56u && (unsigned)ix < 56u)
        v = xb[(size_t)c*L_ + iy*56 + ix];
      const int spat = ry*64 + wc;
      xt2[spat*72 + (((c>>3) + 2*spat) & 7)*8 + (c & 7)] = f2bf(v);
    }
  }
  __syncthreads();

  // ---- a2 partials: row = mq*16+lr; ih splits the 18 z-steps ----
  {
    const int l_  = l0 + mq*16 + lr;
    const int hwB = (l_/56 - h0)*64 + (l_ - (l_/56)*56);
    float s2 = 0.f;
    #pragma unroll
    for (int z = 0; z < 9; ++z){
      const int uu = (ih*9 + z)*4 + g;
      const int rr = uu >> 3, o = uu & 7;
      const int di = (rr >= 3) + (rr >= 6);
      const int spat = hwB + di*64 + (rr - di*3);
      u16x8 v8 = *(const u16x8*)&xt2[spat*72 + ((o + 2*spat) & 7)*8];
      #pragma unroll
      for (int c = 0; c < 8; ++c){
        const float vr = bits2f(v8[c]);
        s2 = fmaf(vr, vr, s2);
      }
    }
    s2 += __shfl_xor(s2, 16);
    s2 += __shfl_xor(s2, 32);
    if (g == 0) a2l[ih*64 + mq*16 + lr] = s2;
  }
  __syncthreads();               // a2l visible

  // ================= phase 1: G = A * Cb^T (no barriers) =================
  int hw2[2];
  #pragma unroll
  for (int i = 0; i < 2; ++i){
    const int li = l0 + ih*32 + i*16 + lr;
    const int hi = li / 56;
    hw2[i] = (hi - h0)*64 + (li - hi*56);
  }

  f32x4 acc[2][4];
  #pragma unroll
  for (int i = 0; i < 2; ++i)
    #pragma unroll
    for (int j = 0; j < 4; ++j) acc[i][j] = (f32x4){0.f,0.f,0.f,0.f};

  bf16x8 bbc[4], bbn[4];
  #pragma unroll
  for (int j = 0; j < 4; ++j)
    bbc[j] = *(const bf16x8*)(CbP + (((size_t)(mq*4 + j)*18 + 0)*64 + lane)*8);

  #pragma unroll
  for (int kk = 0; kk < 18; ++kk){
    const int idx = kk*4 + g;
    const int rr = idx >> 3, o = idx & 7;
    const int di = (rr >= 3) + (rr >= 6);
    const int doff = di*64 + (rr - di*3);
    bf16x8 af[2];
    #pragma unroll
    for (int i = 0; i < 2; ++i){
      const int spat = hw2[i] + doff;
      af[i] = *(const bf16x8*)&xt2[spat*72 + ((o + 2*spat) & 7)*8];
    }
    if (kk + 1 < 18){
      #pragma unroll
      for (int j = 0; j < 4; ++j)
        bbn[j] = *(const bf16x8*)(CbP + (((size_t)(mq*4 + j)*18 + (kk+1))*64 + lane)*8);
    }
    #pragma unroll
    for (int i = 0; i < 2; ++i)
      #pragma unroll
      for (int j = 0; j < 4; ++j)
        acc[i][j] = __builtin_amdgcn_mfma_f32_16x16x32_bf16(af[i], bbc[j], acc[i][j], 0, 0, 0);
    if (kk + 1 < 18){
      #pragma unroll
      for (int j = 0; j < 4; ++j) bbc[j] = bbn[j];
    }
  }

  // ---- softmax over all 256 m (rows split by ih, cols by mq) ----
  float a2r[2][4], b2r[4];
  #pragma unroll
  for (int i = 0; i < 2; ++i)
    #pragma unroll
    for (int r = 0; r < 4; ++r){
      const int row = ih*32 + i*16 + g*4 + r;
      a2r[i][r] = a2l[row] + a2l[64 + row];
    }
  #pragma unroll
  for (int j = 0; j < 4; ++j) b2r[j] = b2v[mq*64 + j*16 + lr];

  float rmax[2][4];
  #pragma unroll
  for (int i = 0; i < 2; ++i)
    #pragma unroll
    for (int r = 0; r < 4; ++r) rmax[i][r] = -3.4e38f;

  #pragma unroll
  for (int i = 0; i < 2; ++i)
    #pragma unroll
    for (int j = 0; j < 4; ++j)
      #pragma unroll
      for (int r = 0; r < 4; ++r){
        float d2 = fmaxf(a2r[i][r] + b2r[j] - 2.f*acc[i][j][r], 1e-12f);
        float lg = -temp * sqrtf(d2);
        acc[i][j][r] = lg;
        rmax[i][r] = fmaxf(rmax[i][r], lg);
      }
  #pragma unroll
  for (int i = 0; i < 2; ++i)
    #pragma unroll
    for (int r = 0; r < 4; ++r){
      float v = rmax[i][r];
      v = fmaxf(v, __shfl_xor(v, 1));
      v = fmaxf(v, __shfl_xor(v, 2));
      v = fmaxf(v, __shfl_xor(v, 4));
      v = fmaxf(v, __shfl_xor(v, 8));
      rmax[i][r] = v;
    }
  __syncthreads();
  if (lr == 0){
    #pragma unroll
    for (int i = 0; i < 2; ++i)
      #pragma unroll
      for (int r = 0; r < 4; ++r)
        red[mq*64 + ih*32 + i*16 + g*4 + r] = rmax[i][r];
  }
  __syncthreads();
  #pragma unroll
  for (int i = 0; i < 2; ++i)
    #pragma unroll
    for (int r = 0; r < 4; ++r){
      const int row = ih*32 + i*16 + g*4 + r;
      rmax[i][r] = fmaxf(fmaxf(red[row], red[64+row]), fmaxf(red[128+row], red[192+row]));
    }
  float rsum[2][4];
  #pragma unroll
  for (int i = 0; i < 2; ++i)
    #pragma unroll
    for (int r = 0; r < 4; ++r) rsum[i][r] = 0.f;
  #pragma unroll
  for (int i = 0; i < 2; ++i)
    #pragma unroll
    for (int j = 0; j < 4; ++j)
      #pragma unroll
      for (int r = 0; r < 4; ++r){
        float pe = __expf(acc[i][j][r] - rmax[i][r]);
        acc[i][j][r] = pe;
        rsum[i][r] += pe;
      }
  #pragma unroll
  for (int i = 0; i < 2; ++i)
    #pragma unroll
    for (int r = 0; r < 4; ++r){
      float v = rsum[i][r];
      v += __shfl_xor(v, 1);
      v += __shfl_xor(v, 2);
      v += __shfl_xor(v, 4);
      v += __shfl_xor(v, 8);
      rsum[i][r] = v;
    }
  __syncthreads();
  if (lr == 0){
    #pragma unroll
    for (int i = 0; i < 2; ++i)
      #pragma unroll
      for (int r = 0; r < 4; ++r)
        red[mq*64 + ih*32 + i*16 + g*4 + r] = rsum[i][r];
  }
  __syncthreads();
  #pragma unroll
  for (int i = 0; i < 2; ++i)
    #pragma unroll
    for (int r = 0; r < 4; ++r){
      const int row = ih*32 + i*16 + g*4 + r;
      const float invr = 1.f / (red[row] + red[64+row] + red[128+row] + red[192+row]);
      #pragma unroll
      for (int j = 0; j < 4; ++j)
        Sl[(size_t)row*264 + mq*64 + j*16 + lr] = f2bf(acc[i][j][r] * invr);
    }
  __syncthreads();                 // Sl visible

  // ========== phase 2: T = Sl * Ct (no barriers, batch frag loads) ==========
  f32x4 acc2[2][9];
  #pragma unroll
  for (int i = 0; i < 2; ++i)
    #pragma unroll
    for (int j = 0; j < 9; ++j) acc2[i][j] = (f32x4){0.f,0.f,0.f,0.f};

  for (int mc = 0; mc < 8; ++mc){
    bf16x8 af2[2], bb2[9];
    #pragma unroll
    for (int i = 0; i < 2; ++i)
      af2[i] = *(const bf16x8*)&Sl[(size_t)(ih*32 + i*16 + lr)*264 + mc*32 + g*8];
    #pragma unroll
    for (int j = 0; j < 9; ++j)
      bb2[j] = *(const bf16x8*)(CtP + (((size_t)(mq*9 + j)*8 + mc)*64 + lane)*8);
    #pragma unroll
    for (int j = 0; j < 9; ++j)
      #pragma unroll
      for (int i = 0; i < 2; ++i)
        acc2[i][j] = __builtin_amdgcn_mfma_f32_16x16x32_bf16(af2[i], bb2[j], acc2[i][j], 0, 0, 0);
  }

  // ---- F write: two 288-p halves; skip term re-gathered from xt2 ----------
  const float inv = 1.f / (temp + 1.f);
  const float tscale = temp * inv;
  #pragma unroll
  for (int hh = 0; hh < 2; ++hh){
    __syncthreads();               // Fl region free
    if ((mq >> 1) == hh){
      const int pbase = (mq & 1) * 144;
      #pragma unroll
      for (int i = 0; i < 2; ++i)
        #pragma unroll
        for (int j = 0; j < 9; ++j)
          #pragma unroll
          for (int r = 0; r < 4; ++r)
            Fl[(ih*32 + i*16 + g*4 + r)*296 + pbase + j*16 + lr] = f2bf(acc2[i][j][r] * tscale);
    }
    __syncthreads();
    for (int v = t; v < 2304; v += 512){
      const int row = v / 36, col = (v - row*36) * 8;
      u16x8 tv = *(const u16x8*)&Fl[row*296 + col];
      const int p0 = hh*288 + col;
      int ch2 = p0 / 9;
      int rr2 = p0 - ch2*9;
      const int l2 = l0 + row;
      const int h2 = l2 / 56;
      const int hb2 = (h2 - h0)*64 + (l2 - h2*56);
      u16x8 o;
      #pragma unroll
      for (int c2 = 0; c2 < 8; ++c2){
        const int di2 = (rr2 >= 3) + (rr2 >= 6);
        const int spat = hb2 + di2*64 + (rr2 - di2*3);
        const u16 av_ = xt2[spat*72 + (((ch2>>3) + 2*spat) & 7)*8 + (ch2 & 7)];
        o[c2] = f2bf(bits2f(tv[c2]) + bits2f(av_) * inv);
        const bool w9 = (rr2 == 8);
        rr2 = w9 ? 0 : rr2 + 1;
        ch2 += w9 ? 1 : 0;
      }
      *(u16x8*)(F + (size_t)(n0 + row)*P_ + hh*288 + col) = o;
    }
  }
}

// ---- K4: MFMA GEMM out = WbP * F (+bias), mask fused into F staging --------
__global__ __launch_bounds__(256) void k4_conv(const u16* __restrict__ F,
    const u16* __restrict__ WbP, const float* __restrict__ bias,
    float* __restrict__ out){
  __shared__ short Fl[128*40];
  const int t = threadIdx.x;
  const int lane = t & 63;
  const int w = t >> 6;
  const int wn = w >> 1;
  const int ws = w & 1;
  const int g  = lane >> 4;
  const int lr = lane & 15;
  const int b  = blockIdx.y;
  const int s0 = blockIdx.x * 128;
  const u16* Fb = F + (size_t)b * ((size_t)P_ * L_);

  f32x4 acc[4][4];
  #pragma unroll
  for (int i = 0; i < 4; ++i)
    #pragma unroll
    for (int j = 0; j < 4; ++j) acc[i][j] = (f32x4){0.f,0.f,0.f,0.f};

  for (int step = 0; step < 18; ++step){
    const int q0 = step * 32;
    __syncthreads();
    #pragma unroll
    for (int e = 0; e < 2; ++e){
      const int c = t + e*256;
      const int ql = c & 31, sch = c >> 5;
      const int q  = q0 + ql;
      const int sbase = s0 + sch*8;
      const int scl = (sbase < L_ - 8) ? sbase : (L_ - 8);
      u16x8 v = *(const u16x8*)(Fb + (size_t)q*L_ + scl);
      const int q3 = q/3;
      const bool kx0 = (q - q3*3) == 0;
      const bool ky0 = (q3 % 3) == 0;
      const int r0 = sbase % 56;
      #pragma unroll
      for (int u = 0; u < 8; ++u){
        const bool m0 = ky0 && (sbase + u) < 56;
        const bool m1 = kx0 && ((r0 + u) == 0 || (r0 + u) == 56);
        Fl[(sch*8 + u)*40 + ql] = (m0 || m1) ? (short)0 : (short)v[u];
      }
    }
    __syncthreads();
    bf16x8 af[4], bb[4];
    #pragma unroll
    for (int i = 0; i < 4; ++i)
      af[i] = *(const bf16x8*)(WbP + (((size_t)(wn*4 + i)*18 + step)*64 + lane)*8);
    #pragma unroll
    for (int j = 0; j < 4; ++j)
      bb[j] = *(const bf16x8*)&Fl[(ws*64 + j*16 + lr)*40 + g*8];
    #pragma unroll
    for (int i = 0; i < 4; ++i)
      #pragma unroll
      for (int j = 0; j < 4; ++j)
        acc[i][j] = __builtin_amdgcn_mfma_f32_16x16x32_bf16(af[i], bb[j], acc[i][j], 0, 0, 0);
  }

  #pragma unroll
  for (int i = 0; i < 4; ++i)
    #pragma unroll
    for (int r = 0; r < 4; ++r){
      const int co = wn*64 + i*16 + g*4 + r;
      const float bv = bias[co];
      #pragma unroll
      for (int j = 0; j < 4; ++j){
        const int s = s0 + ws*64 + j*16 + lr;
        if (s < L_) out[((size_t)b*COUT + co)*L_ + s] = acc[i][j][r] + bv;
      }
    }
}

extern "C" void kernel_launch(void* const* d_in, const int* in_sizes, int n_in,
                              void* d_out, int out_size, void* d_ws, size_t ws_size,
                              hipStream_t stream){
  const float* x      = (const float*)d_in[0];
  const float* weight = (const float*)d_in[1];
  const float* bias   = (const float*)d_in[2];
  const float* cc     = (const float*)d_in[3];
  const float* temp_p = (const float*)d_in[4];
  float* out = (float*)d_out;

  char* ws = (char*)d_ws;
  u16*   F   = (u16*)(ws);                 // 115,605,504 B (standard [n][p])
  float* b2v = (float*)(ws + 115605504);   //       1,024 B
  u16*   CbP = (u16*)(ws + 115606528);     //     294,912 B
  u16*   CtP = (u16*)(ws + 115901440);     //     294,912 B
  u16*   WbP = (u16*)(ws + 116196352);     //     147,456 B

  k0_prep <<<436,          256, 0, stream>>>(cc, weight, CbP, CtP, b2v, WbP);
  k123    <<<N_/64,        512, 0, stream>>>(x, CbP, CtP, b2v, temp_p, F);
  k4_conv <<<dim3(25, B_), 256, 0, stream>>>(F, WbP, bias, out);
}

// Round 20
// 238.691 us; speedup vs baseline: 1.1652x; 1.0665x over previous
//
#include <hip/hip_runtime.h>
#include <hip/hip_bf16.h>

#define B_    32
#define CIN   64
#define HW    56
#define COUT  128
#define M_    256
#define P_    576
#define L_    3136
#define N_    100352

typedef __hip_bfloat16 bf16;
typedef unsigned short u16;
typedef __attribute__((ext_vector_type(8))) short bf16x8;
typedef __attribute__((ext_vector_type(8))) unsigned short u16x8;
typedef __attribute__((ext_vector_type(4))) float f32x4;

__device__ __forceinline__ float bits2f(u16 u){ return __uint_as_float(((unsigned)u) << 16); }
__device__ __forceinline__ u16 f2bf(float f){
  bf16 h = __float2bfloat16(f);
  return *(u16*)&h;
}

// ---- K0: fragment-major operand layouts + b2 -------------------------------
__global__ __launch_bounds__(256) void k0_prep(const float* __restrict__ C,
                                               const float* __restrict__ W,
                                               u16* __restrict__ CbP, u16* __restrict__ CtP,
                                               float* __restrict__ b2v, u16* __restrict__ WbP){
  __shared__ float red[4];
  const int t = threadIdx.x;
  const int bid = blockIdx.x;
  if (bid < M_){
    const int m = bid;
    float s = 0.f;
    for (int p = t; p < P_; p += 256){
      float vr = bits2f(f2bf(C[(size_t)m*P_ + p]));
      s += vr*vr;
    }
    #pragma unroll
    for (int off = 32; off >= 1; off >>= 1) s += __shfl_xor(s, off);
    if ((t & 63) == 0) red[t >> 6] = s;
    __syncthreads();
    if (t == 0) b2v[m] = red[0] + red[1] + red[2] + red[3];
  } else if (bid < M_ + 72){
    const int u = (bid - M_)*256 + t;
    const int f = u >> 6, lane = u & 63;
    const int g = lane >> 4, lr = lane & 15;
    const int k = f % 18, fj = f / 18;
    const int j = fj & 3, wvq = fj >> 2;
    const int m = wvq*64 + j*16 + lr;
    const int idx = k*4 + g;
    const int o = idx & 7, rr = idx >> 3;
    u16x8 o8;
    #pragma unroll
    for (int c = 0; c < 8; ++c) o8[c] = f2bf(C[(size_t)m*P_ + (o*8 + c)*9 + rr]);
    *(u16x8*)&CbP[(size_t)u*8] = o8;
  } else if (bid < M_ + 144){
    const int u = (bid - M_ - 72)*256 + t;
    const int f = u >> 6, lane = u & 63;
    const int g = lane >> 4, lr = lane & 15;
    const int mc = f & 7, fj = f >> 3;
    const int j = fj % 9, q = fj / 9;
    const int p = q*144 + j*16 + lr;
    const int m = mc*32 + g*8;
    u16x8 o8;
    #pragma unroll
    for (int c = 0; c < 8; ++c) o8[c] = f2bf(C[(size_t)(m + c)*P_ + p]);
    *(u16x8*)&CtP[(size_t)u*8] = o8;
  } else {
    const int u = (bid - M_ - 144)*256 + t;
    const int f = u >> 6, lane = u & 63;
    const int g = lane >> 4, lr = lane & 15;
    const int k = f % 18, fi = f / 18;
    const int i = fi & 3, wn = fi >> 2;
    const int co = wn*64 + i*16 + lr;
    const int q = k*32 + g*8;
    u16x8 o8;
    #pragma unroll
    for (int c = 0; c < 8; ++c) o8[c] = f2bf(W[(size_t)co*P_ + q + c]);
    *(u16x8*)&WbP[(size_t)u*8] = o8;
  }
}

// ---- K123: fused unfold+assign+transform. 512 threads, 8 waves. ------------
// wv = ih*4+mq: ih = row-half (32 rows), mq = m/p-quarter.
// XCD-aware block swizzle (nwg = 1568 = 8*196, bijective).
__global__ __launch_bounds__(512, 4) void k123(const float* __restrict__ x,
    const u16* __restrict__ CbP, const u16* __restrict__ CtP,
    const float* __restrict__ b2v, const float* __restrict__ temp_p,
    u16* __restrict__ F){
  __shared__ __align__(16) char lds[76288];
  u16*   xt2 = (u16*)lds;                 // 256 spat x 72 u16 = 36864 B
  char*  Bz  = lds + 36864;               // 37888 B overlay: Sl / Fl
  u16*   Sl  = (u16*)Bz;                  // 64 x 264 u16 = 33792 B
  u16*   Fl  = (u16*)Bz;                  // 64 x 296 u16 = 37888 B
  float* a2l = (float*)(lds + 74752);     // 2 x 64 f (partials by ih)
  float* red = (float*)(lds + 75264);     // 256 f

  const int t = threadIdx.x;
  const int lane = t & 63;
  const int wv = t >> 6;                  // 0..7
  const int ih = wv >> 2;                 // row half
  const int mq = wv & 3;                  // m/p quarter
  const int g  = lane >> 4;
  const int lr = lane & 15;
  const int blk_raw = blockIdx.x;
  const int blk = (blk_raw & 7) * 196 + (blk_raw >> 3);   // XCD-chunked
  const int n0 = blk * 64;
  const int b  = n0 / L_;
  const int l0 = n0 - b * L_;
  const int h0 = l0 / 56;
  const float temp = *temp_p;

  // ---- stage x window transposed: xt2[spat=ry*64+wc][swz(ch)] ----
  const float* xb = x + (size_t)b * CIN * L_;
  {
    const int wc = t & 63;
    const int ix = wc - 1;
    #pragma unroll 4
    for (int iter = 0; iter < 32; ++iter){
      const int cw = (t >> 6) + iter*8;    // 0..255
      const int c  = cw & 63;
      const int ry = cw >> 6;
      const int iy = h0 - 1 + ry;
      float v = 0.f;
      if ((unsigned)iy < 56u && (unsigned)ix < 56u)
        v = xb[(size_t)c*L_ + iy*56 + ix];
      const int spat = ry*64 + wc;
      xt2[spat*72 + (((c>>3) + 2*spat) & 7)*8 + (c & 7)] = f2bf(v);
    }
  }
  __syncthreads();

  // ---- a2 partials: row = mq*16+lr; ih splits the 18 z-steps ----
  {
    const int l_  = l0 + mq*16 + lr;
    const int hwB = (l_/56 - h0)*64 + (l_ - (l_/56)*56);
    float s2 = 0.f;
    #pragma unroll
    for (int z = 0; z < 9; ++z){
      const int uu = (ih*9 + z)*4 + g;
      const int rr = uu >> 3, o = uu & 7;
      const int di = (rr >= 3) + (rr >= 6);
      const int spat = hwB + di*64 + (rr - di*3);
      u16x8 v8 = *(const u16x8*)&xt2[spat*72 + ((o + 2*spat) & 7)*8];
      #pragma unroll
      for (int c = 0; c < 8; ++c){
        const float vr = bits2f(v8[c]);
        s2 = fmaf(vr, vr, s2);
      }
    }
    s2 += __shfl_xor(s2, 16);
    s2 += __shfl_xor(s2, 32);
    if (g == 0) a2l[ih*64 + mq*16 + lr] = s2;
  }
  __syncthreads();               // a2l visible

  // ================= phase 1: G = A * Cb^T (no barriers) =================
  int hw2[2];
  #pragma unroll
  for (int i = 0; i < 2; ++i){
    const int li = l0 + ih*32 + i*16 + lr;
    const int hi = li / 56;
    hw2[i] = (hi - h0)*64 + (li - hi*56);
  }

  f32x4 acc[2][4];
  #pragma unroll
  for (int i = 0; i < 2; ++i)
    #pragma unroll
    for (int j = 0; j < 4; ++j) acc[i][j] = (f32x4){0.f,0.f,0.f,0.f};

  bf16x8 bbc[4], bbn[4];
  #pragma unroll
  for (int j = 0; j < 4; ++j)
    bbc[j] = *(const bf16x8*)(CbP + (((size_t)(mq*4 + j)*18 + 0)*64 + lane)*8);

  #pragma unroll
  for (int kk = 0; kk < 18; ++kk){
    const int idx = kk*4 + g;
    const int rr = idx >> 3, o = idx & 7;
    const int di = (rr >= 3) + (rr >= 6);
    const int doff = di*64 + (rr - di*3);
    bf16x8 af[2];
    #pragma unroll
    for (int i = 0; i < 2; ++i){
      const int spat = hw2[i] + doff;
      af[i] = *(const bf16x8*)&xt2[spat*72 + ((o + 2*spat) & 7)*8];
    }
    if (kk + 1 < 18){
      #pragma unroll
      for (int j = 0; j < 4; ++j)
        bbn[j] = *(const bf16x8*)(CbP + (((size_t)(mq*4 + j)*18 + (kk+1))*64 + lane)*8);
    }
    #pragma unroll
    for (int i = 0; i < 2; ++i)
      #pragma unroll
      for (int j = 0; j < 4; ++j)
        acc[i][j] = __builtin_amdgcn_mfma_f32_16x16x32_bf16(af[i], bbc[j], acc[i][j], 0, 0, 0);
    if (kk + 1 < 18){
      #pragma unroll
      for (int j = 0; j < 4; ++j) bbc[j] = bbn[j];
    }
  }

  // ---- softmax over all 256 m (rows split by ih, cols by mq) ----
  float a2r[2][4], b2r[4];
  #pragma unroll
  for (int i = 0; i < 2; ++i)
    #pragma unroll
    for (int r = 0; r < 4; ++r){
      const int row = ih*32 + i*16 + g*4 + r;
      a2r[i][r] = a2l[row] + a2l[64 + row];
    }
  #pragma unroll
  for (int j = 0; j < 4; ++j) b2r[j] = b2v[mq*64 + j*16 + lr];

  float rmax[2][4];
  #pragma unroll
  for (int i = 0; i < 2; ++i)
    #pragma unroll
    for (int r = 0; r < 4; ++r) rmax[i][r] = -3.4e38f;

  #pragma unroll
  for (int i = 0; i < 2; ++i)
    #pragma unroll
    for (int j = 0; j < 4; ++j)
      #pragma unroll
      for (int r = 0; r < 4; ++r){
        float d2 = fmaxf(a2r[i][r] + b2r[j] - 2.f*acc[i][j][r], 1e-12f);
        float lg = -temp * sqrtf(d2);
        acc[i][j][r] = lg;
        rmax[i][r] = fmaxf(rmax[i][r], lg);
      }
  #pragma unroll
  for (int i = 0; i < 2; ++i)
    #pragma unroll
    for (int r = 0; r < 4; ++r){
      float v = rmax[i][r];
      v = fmaxf(v, __shfl_xor(v, 1));
      v = fmaxf(v, __shfl_xor(v, 2));
      v = fmaxf(v, __shfl_xor(v, 4));
      v = fmaxf(v, __shfl_xor(v, 8));
      rmax[i][r] = v;
    }
  __syncthreads();
  if (lr == 0){
    #pragma unroll
    for (int i = 0; i < 2; ++i)
      #pragma unroll
      for (int r = 0; r < 4; ++r)
        red[mq*64 + ih*32 + i*16 + g*4 + r] = rmax[i][r];
  }
  __syncthreads();
  #pragma unroll
  for (int i = 0; i < 2; ++i)
    #pragma unroll
    for (int r = 0; r < 4; ++r){
      const int row = ih*32 + i*16 + g*4 + r;
      rmax[i][r] = fmaxf(fmaxf(red[row], red[64+row]), fmaxf(red[128+row], red[192+row]));
    }
  float rsum[2][4];
  #pragma unroll
  for (int i = 0; i < 2; ++i)
    #pragma unroll
    for (int r = 0; r < 4; ++r) rsum[i][r] = 0.f;
  #pragma unroll
  for (int i = 0; i < 2; ++i)
    #pragma unroll
    for (int j = 0; j < 4; ++j)
      #pragma unroll
      for (int r = 0; r < 4; ++r){
        float pe = __expf(acc[i][j][r] - rmax[i][r]);
        acc[i][j][r] = pe;
        rsum[i][r] += pe;
      }
  #pragma unroll
  for (int i = 0; i < 2; ++i)
    #pragma unroll
    for (int r = 0; r < 4; ++r){
      float v = rsum[i][r];
      v += __shfl_xor(v, 1);
      v += __shfl_xor(v, 2);
      v += __shfl_xor(v, 4);
      v += __shfl_xor(v, 8);
      rsum[i][r] = v;
    }
  __syncthreads();
  if (lr == 0){
    #pragma unroll
    for (int i = 0; i < 2; ++i)
      #pragma unroll
      for (int r = 0; r < 4; ++r)
        red[mq*64 + ih*32 + i*16 + g*4 + r] = rsum[i][r];
  }
  __syncthreads();
  #pragma unroll
  for (int i = 0; i < 2; ++i)
    #pragma unroll
    for (int r = 0; r < 4; ++r){
      const int row = ih*32 + i*16 + g*4 + r;
      const float invr = 1.f / (red[row] + red[64+row] + red[128+row] + red[192+row]);
      #pragma unroll
      for (int j = 0; j < 4; ++j)
        Sl[(size_t)row*264 + mq*64 + j*16 + lr] = f2bf(acc[i][j][r] * invr);
    }
  __syncthreads();                 // Sl visible

  // ========== phase 2: T = Sl * Ct (no barriers, batch frag loads) ==========
  f32x4 acc2[2][9];
  #pragma unroll
  for (int i = 0; i < 2; ++i)
    #pragma unroll
    for (int j = 0; j < 9; ++j) acc2[i][j] = (f32x4){0.f,0.f,0.f,0.f};

  for (int mc = 0; mc < 8; ++mc){
    bf16x8 af2[2], bb2[9];
    #pragma unroll
    for (int i = 0; i < 2; ++i)
      af2[i] = *(const bf16x8*)&Sl[(size_t)(ih*32 + i*16 + lr)*264 + mc*32 + g*8];
    #pragma unroll
    for (int j = 0; j < 9; ++j)
      bb2[j] = *(const bf16x8*)(CtP + (((size_t)(mq*9 + j)*8 + mc)*64 + lane)*8);
    #pragma unroll
    for (int j = 0; j < 9; ++j)
      #pragma unroll
      for (int i = 0; i < 2; ++i)
        acc2[i][j] = __builtin_amdgcn_mfma_f32_16x16x32_bf16(af2[i], bb2[j], acc2[i][j], 0, 0, 0);
  }

  // ---- F write: two 288-p halves; skip term re-gathered from xt2 ----------
  const float inv = 1.f / (temp + 1.f);
  const float tscale = temp * inv;
  #pragma unroll
  for (int hh = 0; hh < 2; ++hh){
    __syncthreads();               // Fl region free
    if ((mq >> 1) == hh){
      const int pbase = (mq & 1) * 144;
      #pragma unroll
      for (int i = 0; i < 2; ++i)
        #pragma unroll
        for (int j = 0; j < 9; ++j)
          #pragma unroll
          for (int r = 0; r < 4; ++r)
            Fl[(ih*32 + i*16 + g*4 + r)*296 + pbase + j*16 + lr] = f2bf(acc2[i][j][r] * tscale);
    }
    __syncthreads();
    for (int v = t; v < 2304; v += 512){
      const int row = v / 36, col = (v - row*36) * 8;
      u16x8 tv = *(const u16x8*)&Fl[row*296 + col];
      const int p0 = hh*288 + col;
      int ch2 = p0 / 9;
      int rr2 = p0 - ch2*9;
      const int l2 = l0 + row;
      const int h2 = l2 / 56;
      const int hb2 = (h2 - h0)*64 + (l2 - h2*56);
      u16x8 o;
      #pragma unroll
      for (int c2 = 0; c2 < 8; ++c2){
        const int di2 = (rr2 >= 3) + (rr2 >= 6);
        const int spat = hb2 + di2*64 + (rr2 - di2*3);
        const u16 av_ = xt2[spat*72 + (((ch2>>3) + 2*spat) & 7)*8 + (ch2 & 7)];
        o[c2] = f2bf(bits2f(tv[c2]) + bits2f(av_) * inv);
        const bool w9 = (rr2 == 8);
        rr2 = w9 ? 0 : rr2 + 1;
        ch2 += w9 ? 1 : 0;
      }
      *(u16x8*)(F + (size_t)(n0 + row)*P_ + hh*288 + col) = o;
    }
  }
}

// ---- K4: MFMA GEMM out = WbP * F (+bias), mask fused into F staging --------
__global__ __launch_bounds__(256) void k4_conv(const u16* __restrict__ F,
    const u16* __restrict__ WbP, const float* __restrict__ bias,
    float* __restrict__ out){
  __shared__ short Fl[128*40];
  const int t = threadIdx.x;
  const int lane = t & 63;
  const int w = t >> 6;
  const int wn = w >> 1;
  const int ws = w & 1;
  const int g  = lane >> 4;
  const int lr = lane & 15;
  const int b  = blockIdx.y;
  const int s0 = blockIdx.x * 128;
  const u16* Fb = F + (size_t)b * ((size_t)P_ * L_);

  f32x4 acc[4][4];
  #pragma unroll
  for (int i = 0; i < 4; ++i)
    #pragma unroll
    for (int j = 0; j < 4; ++j) acc[i][j] = (f32x4){0.f,0.f,0.f,0.f};

  for (int step = 0; step < 18; ++step){
    const int q0 = step * 32;
    __syncthreads();
    #pragma unroll
    for (int e = 0; e < 2; ++e){
      const int c = t + e*256;
      const int ql = c & 31, sch = c >> 5;
      const int q  = q0 + ql;
      const int sbase = s0 + sch*8;
      const int scl = (sbase < L_ - 8) ? sbase : (L_ - 8);
      u16x8 v = *(const u16x8*)(Fb + (size_t)q*L_ + scl);
      const int q3 = q/3;
      const bool kx0 = (q - q3*3) == 0;
      const bool ky0 = (q3 % 3) == 0;
      const int r0 = sbase % 56;
      #pragma unroll
      for (int u = 0; u < 8; ++u){
        const bool m0 = ky0 && (sbase + u) < 56;
        const bool m1 = kx0 && ((r0 + u) == 0 || (r0 + u) == 56);
        Fl[(sch*8 + u)*40 + ql] = (m0 || m1) ? (short)0 : (short)v[u];
      }
    }
    __syncthreads();
    bf16x8 af[4], bb[4];
    #pragma unroll
    for (int i = 0; i < 4; ++i)
      af[i] = *(const bf16x8*)(WbP + (((size_t)(wn*4 + i)*18 + step)*64 + lane)*8);
    #pragma unroll
    for (int j = 0; j < 4; ++j)
      bb[j] = *(const bf16x8*)&Fl[(ws*64 + j*16 + lr)*40 + g*8];
    #pragma unroll
    for (int i = 0; i < 4; ++i)
      #pragma unroll
      for (int j = 0; j < 4; ++j)
        acc[i][j] = __builtin_amdgcn_mfma_f32_16x16x32_bf16(af[i], bb[j], acc[i][j], 0, 0, 0);
  }

  #pragma unroll
  for (int i = 0; i < 4; ++i)
    #pragma unroll
    for (int r = 0; r < 4; ++r){
      const int co = wn*64 + i*16 + g*4 + r;
      const float bv = bias[co];
      #pragma unroll
      for (int j = 0; j < 4; ++j){
        const int s = s0 + ws*64 + j*16 + lr;
        if (s < L_) out[((size_t)b*COUT + co)*L_ + s] = acc[i][j][r] + bv;
      }
    }
}

extern "C" void kernel_launch(void* const* d_in, const int* in_sizes, int n_in,
                              void* d_out, int out_size, void* d_ws, size_t ws_size,
                              hipStream_t stream){
  const float* x      = (const float*)d_in[0];
  const float* weight = (const float*)d_in[1];
  const float* bias   = (const float*)d_in[2];
  const float* cc     = (const float*)d_in[3];
  const float* temp_p = (const float*)d_in[4];
  float* out = (float*)d_out;

  char* ws = (char*)d_ws;
  u16*   F   = (u16*)(ws);                 // 115,605,504 B (standard [n][p])
  float* b2v = (float*)(ws + 115605504);   //       1,024 B
  u16*   CbP = (u16*)(ws + 115606528);     //     294,912 B
  u16*   CtP = (u16*)(ws + 115901440);     //     294,912 B
  u16*   WbP = (u16*)(ws + 116196352);     //     147,456 B

  k0_prep <<<436,          256, 0, stream>>>(cc, weight, CbP, CtP, b2v, WbP);
  k123    <<<N_/64,        512, 0, stream>>>(x, CbP, CtP, b2v, temp_p, F);
  k4_conv <<<dim3(25, B_), 256, 0, stream>>>(F, WbP, bias, out);
}

// Round 21
// 214.364 us; speedup vs baseline: 1.2974x; 1.1135x over previous
//
#include <hip/hip_runtime.h>
#include <hip/hip_bf16.h>

#define B_    32
#define CIN   64
#define HW    56
#define COUT  128
#define M_    256
#define P_    576
#define L_    3136
#define N_    100352

typedef __hip_bfloat16 bf16;
typedef unsigned short u16;
typedef __attribute__((ext_vector_type(8))) short bf16x8;
typedef __attribute__((ext_vector_type(8))) unsigned short u16x8;
typedef __attribute__((ext_vector_type(4))) float f32x4;

__device__ __forceinline__ float bits2f(u16 u){ return __uint_as_float(((unsigned)u) << 16); }
__device__ __forceinline__ u16 f2bf(float f){
  bf16 h = __float2bfloat16(f);
  return *(u16*)&h;
}

// ---- K0: fragment-major operand layouts + b2 -------------------------------
__global__ __launch_bounds__(256) void k0_prep(const float* __restrict__ C,
                                               const float* __restrict__ W,
                                               u16* __restrict__ CbP, u16* __restrict__ CtP,
                                               float* __restrict__ b2v, u16* __restrict__ WbP){
  __shared__ float red[4];
  const int t = threadIdx.x;
  const int bid = blockIdx.x;
  if (bid < M_){
    const int m = bid;
    float s = 0.f;
    for (int p = t; p < P_; p += 256){
      float vr = bits2f(f2bf(C[(size_t)m*P_ + p]));
      s += vr*vr;
    }
    #pragma unroll
    for (int off = 32; off >= 1; off >>= 1) s += __shfl_xor(s, off);
    if ((t & 63) == 0) red[t >> 6] = s;
    __syncthreads();
    if (t == 0) b2v[m] = red[0] + red[1] + red[2] + red[3];
  } else if (bid < M_ + 72){
    const int u = (bid - M_)*256 + t;
    const int f = u >> 6, lane = u & 63;
    const int g = lane >> 4, lr = lane & 15;
    const int k = f % 18, fj = f / 18;
    const int j = fj & 3, wvq = fj >> 2;
    const int m = wvq*64 + j*16 + lr;
    const int idx = k*4 + g;
    const int o = idx & 7, rr = idx >> 3;
    u16x8 o8;
    #pragma unroll
    for (int c = 0; c < 8; ++c) o8[c] = f2bf(C[(size_t)m*P_ + (o*8 + c)*9 + rr]);
    *(u16x8*)&CbP[(size_t)u*8] = o8;
  } else if (bid < M_ + 144){
    const int u = (bid - M_ - 72)*256 + t;
    const int f = u >> 6, lane = u & 63;
    const int g = lane >> 4, lr = lane & 15;
    const int mc = f & 7, fj = f >> 3;
    const int j = fj % 9, q = fj / 9;
    const int p = q*144 + j*16 + lr;
    const int m = mc*32 + g*8;
    u16x8 o8;
    #pragma unroll
    for (int c = 0; c < 8; ++c) o8[c] = f2bf(C[(size_t)(m + c)*P_ + p]);
    *(u16x8*)&CtP[(size_t)u*8] = o8;
  } else {
    const int u = (bid - M_ - 144)*256 + t;
    const int f = u >> 6, lane = u & 63;
    const int g = lane >> 4, lr = lane & 15;
    const int k = f % 18, fi = f / 18;
    const int i = fi & 3, wn = fi >> 2;
    const int co = wn*64 + i*16 + lr;
    const int q = k*32 + g*8;
    u16x8 o8;
    #pragma unroll
    for (int c = 0; c < 8; ++c) o8[c] = f2bf(W[(size_t)co*P_ + q + c]);
    *(u16x8*)&WbP[(size_t)u*8] = o8;
  }
}

// ---- K123: fused unfold+assign+transform. 512 threads, 8 waves. ------------
// wv = ih*4+mq. XCD-aware block swizzle (nwg = 1568 = 8*196, bijective).
__global__ __launch_bounds__(512, 4) void k123(const float* __restrict__ x,
    const u16* __restrict__ CbP, const u16* __restrict__ CtP,
    const float* __restrict__ b2v, const float* __restrict__ temp_p,
    u16* __restrict__ F){
  __shared__ __align__(16) char lds[76288];
  u16*   xt2 = (u16*)lds;                 // 256 spat x 72 u16 = 36864 B
  char*  Bz  = lds + 36864;               // 37888 B overlay: Sl / Fl
  u16*   Sl  = (u16*)Bz;                  // 64 x 264 u16 = 33792 B
  u16*   Fl  = (u16*)Bz;                  // 64 x 296 u16 = 37888 B
  float* a2l = (float*)(lds + 74752);     // 2 x 64 f (partials by ih)
  float* red = (float*)(lds + 75264);     // 256 f

  const int t = threadIdx.x;
  const int lane = t & 63;
  const int wv = t >> 6;                  // 0..7
  const int ih = wv >> 2;                 // row half
  const int mq = wv & 3;                  // m/p quarter
  const int g  = lane >> 4;
  const int lr = lane & 15;
  const int blk_raw = blockIdx.x;
  const int blk = (blk_raw & 7) * 196 + (blk_raw >> 3);   // XCD-chunked
  const int n0 = blk * 64;
  const int b  = n0 / L_;
  const int l0 = n0 - b * L_;
  const int h0 = l0 / 56;
  const float temp = *temp_p;

  // ---- stage x window transposed: xt2[spat=ry*64+wc][swz(ch)] ----
  const float* xb = x + (size_t)b * CIN * L_;
  {
    const int wc = t & 63;
    const int ix = wc - 1;
    #pragma unroll 4
    for (int iter = 0; iter < 32; ++iter){
      const int cw = (t >> 6) + iter*8;    // 0..255
      const int c  = cw & 63;
      const int ry = cw >> 6;
      const int iy = h0 - 1 + ry;
      float v = 0.f;
      if ((unsigned)iy < 56u && (unsigned)ix < 56u)
        v = xb[(size_t)c*L_ + iy*56 + ix];
      const int spat = ry*64 + wc;
      xt2[spat*72 + (((c>>3) + 2*spat) & 7)*8 + (c & 7)] = f2bf(v);
    }
  }
  __syncthreads();

  // ---- a2 partials: row = mq*16+lr; ih splits the 18 z-steps ----
  {
    const int l_  = l0 + mq*16 + lr;
    const int hwB = (l_/56 - h0)*64 + (l_ - (l_/56)*56);
    float s2 = 0.f;
    #pragma unroll
    for (int z = 0; z < 9; ++z){
      const int uu = (ih*9 + z)*4 + g;
      const int rr = uu >> 3, o = uu & 7;
      const int di = (rr >= 3) + (rr >= 6);
      const int spat = hwB + di*64 + (rr - di*3);
      u16x8 v8 = *(const u16x8*)&xt2[spat*72 + ((o + 2*spat) & 7)*8];
      #pragma unroll
      for (int c = 0; c < 8; ++c){
        const float vr = bits2f(v8[c]);
        s2 = fmaf(vr, vr, s2);
      }
    }
    s2 += __shfl_xor(s2, 16);
    s2 += __shfl_xor(s2, 32);
    if (g == 0) a2l[ih*64 + mq*16 + lr] = s2;
  }
  __syncthreads();               // a2l visible

  // ================= phase 1: G = A * Cb^T (no barriers) =================
  int hw2[2];
  #pragma unroll
  for (int i = 0; i < 2; ++i){
    const int li = l0 + ih*32 + i*16 + lr;
    const int hi = li / 56;
    hw2[i] = (hi - h0)*64 + (li - hi*56);
  }

  f32x4 acc[2][4];
  #pragma unroll
  for (int i = 0; i < 2; ++i)
    #pragma unroll
    for (int j = 0; j < 4; ++j) acc[i][j] = (f32x4){0.f,0.f,0.f,0.f};

  bf16x8 bbc[4], bbn[4];
  #pragma unroll
  for (int j = 0; j < 4; ++j)
    bbc[j] = *(const bf16x8*)(CbP + (((size_t)(mq*4 + j)*18 + 0)*64 + lane)*8);

  #pragma unroll
  for (int kk = 0; kk < 18; ++kk){
    const int idx = kk*4 + g;
    const int rr = idx >> 3, o = idx & 7;
    const int di = (rr >= 3) + (rr >= 6);
    const int doff = di*64 + (rr - di*3);
    bf16x8 af[2];
    #pragma unroll
    for (int i = 0; i < 2; ++i){
      const int spat = hw2[i] + doff;
      af[i] = *(const bf16x8*)&xt2[spat*72 + ((o + 2*spat) & 7)*8];
    }
    if (kk + 1 < 18){
      #pragma unroll
      for (int j = 0; j < 4; ++j)
        bbn[j] = *(const bf16x8*)(CbP + (((size_t)(mq*4 + j)*18 + (kk+1))*64 + lane)*8);
    }
    #pragma unroll
    for (int i = 0; i < 2; ++i)
      #pragma unroll
      for (int j = 0; j < 4; ++j)
        acc[i][j] = __builtin_amdgcn_mfma_f32_16x16x32_bf16(af[i], bbc[j], acc[i][j], 0, 0, 0);
    if (kk + 1 < 18){
      #pragma unroll
      for (int j = 0; j < 4; ++j) bbc[j] = bbn[j];
    }
  }

  // ---- softmax over all 256 m (rows split by ih, cols by mq) ----
  float a2r[2][4], b2r[4];
  #pragma unroll
  for (int i = 0; i < 2; ++i)
    #pragma unroll
    for (int r = 0; r < 4; ++r){
      const int row = ih*32 + i*16 + g*4 + r;
      a2r[i][r] = a2l[row] + a2l[64 + row];
    }
  #pragma unroll
  for (int j = 0; j < 4; ++j) b2r[j] = b2v[mq*64 + j*16 + lr];

  float rmax[2][4];
  #pragma unroll
  for (int i = 0; i < 2; ++i)
    #pragma unroll
    for (int r = 0; r < 4; ++r) rmax[i][r] = -3.4e38f;

  #pragma unroll
  for (int i = 0; i < 2; ++i)
    #pragma unroll
    for (int j = 0; j < 4; ++j)
      #pragma unroll
      for (int r = 0; r < 4; ++r){
        float d2 = fmaxf(a2r[i][r] + b2r[j] - 2.f*acc[i][j][r], 1e-12f);
        float lg = -temp * sqrtf(d2);
        acc[i][j][r] = lg;
        rmax[i][r] = fmaxf(rmax[i][r], lg);
      }
  #pragma unroll
  for (int i = 0; i < 2; ++i)
    #pragma unroll
    for (int r = 0; r < 4; ++r){
      float v = rmax[i][r];
      v = fmaxf(v, __shfl_xor(v, 1));
      v = fmaxf(v, __shfl_xor(v, 2));
      v = fmaxf(v, __shfl_xor(v, 4));
      v = fmaxf(v, __shfl_xor(v, 8));
      rmax[i][r] = v;
    }
  __syncthreads();
  if (lr == 0){
    #pragma unroll
    for (int i = 0; i < 2; ++i)
      #pragma unroll
      for (int r = 0; r < 4; ++r)
        red[mq*64 + ih*32 + i*16 + g*4 + r] = rmax[i][r];
  }
  __syncthreads();
  #pragma unroll
  for (int i = 0; i < 2; ++i)
    #pragma unroll
    for (int r = 0; r < 4; ++r){
      const int row = ih*32 + i*16 + g*4 + r;
      rmax[i][r] = fmaxf(fmaxf(red[row], red[64+row]), fmaxf(red[128+row], red[192+row]));
    }
  float rsum[2][4];
  #pragma unroll
  for (int i = 0; i < 2; ++i)
    #pragma unroll
    for (int r = 0; r < 4; ++r) rsum[i][r] = 0.f;
  #pragma unroll
  for (int i = 0; i < 2; ++i)
    #pragma unroll
    for (int j = 0; j < 4; ++j)
      #pragma unroll
      for (int r = 0; r < 4; ++r){
        float pe = __expf(acc[i][j][r] - rmax[i][r]);
        acc[i][j][r] = pe;
        rsum[i][r] += pe;
      }
  #pragma unroll
  for (int i = 0; i < 2; ++i)
    #pragma unroll
    for (int r = 0; r < 4; ++r){
      float v = rsum[i][r];
      v += __shfl_xor(v, 1);
      v += __shfl_xor(v, 2);
      v += __shfl_xor(v, 4);
      v += __shfl_xor(v, 8);
      rsum[i][r] = v;
    }
  __syncthreads();
  if (lr == 0){
    #pragma unroll
    for (int i = 0; i < 2; ++i)
      #pragma unroll
      for (int r = 0; r < 4; ++r)
        red[mq*64 + ih*32 + i*16 + g*4 + r] = rsum[i][r];
  }
  __syncthreads();
  #pragma unroll
  for (int i = 0; i < 2; ++i)
    #pragma unroll
    for (int r = 0; r < 4; ++r){
      const int row = ih*32 + i*16 + g*4 + r;
      const float invr = 1.f / (red[row] + red[64+row] + red[128+row] + red[192+row]);
      #pragma unroll
      for (int j = 0; j < 4; ++j)
        Sl[(size_t)row*264 + mq*64 + j*16 + lr] = f2bf(acc[i][j][r] * invr);
    }
  __syncthreads();                 // Sl visible

  // ========== phase 2: T = Sl * Ct (no barriers, batch frag loads) ==========
  f32x4 acc2[2][9];
  #pragma unroll
  for (int i = 0; i < 2; ++i)
    #pragma unroll
    for (int j = 0; j < 9; ++j) acc2[i][j] = (f32x4){0.f,0.f,0.f,0.f};

  for (int mc = 0; mc < 8; ++mc){
    bf16x8 af2[2], bb2[9];
    #pragma unroll
    for (int i = 0; i < 2; ++i)
      af2[i] = *(const bf16x8*)&Sl[(size_t)(ih*32 + i*16 + lr)*264 + mc*32 + g*8];
    #pragma unroll
    for (int j = 0; j < 9; ++j)
      bb2[j] = *(const bf16x8*)(CtP + (((size_t)(mq*9 + j)*8 + mc)*64 + lane)*8);
    #pragma unroll
    for (int j = 0; j < 9; ++j)
      #pragma unroll
      for (int i = 0; i < 2; ++i)
        acc2[i][j] = __builtin_amdgcn_mfma_f32_16x16x32_bf16(af2[i], bb2[j], acc2[i][j], 0, 0, 0);
  }

  // ---- F write: two 288-p halves; skip term re-gathered from xt2 ----------
  const float inv = 1.f / (temp + 1.f);
  const float tscale = temp * inv;
  #pragma unroll
  for (int hh = 0; hh < 2; ++hh){
    __syncthreads();               // Fl region free
    if ((mq >> 1) == hh){
      const int pbase = (mq & 1) * 144;
      #pragma unroll
      for (int i = 0; i < 2; ++i)
        #pragma unroll
        for (int j = 0; j < 9; ++j)
          #pragma unroll
          for (int r = 0; r < 4; ++r)
            Fl[(ih*32 + i*16 + g*4 + r)*296 + pbase + j*16 + lr] = f2bf(acc2[i][j][r] * tscale);
    }
    __syncthreads();
    for (int v = t; v < 2304; v += 512){
      const int row = v / 36, col = (v - row*36) * 8;
      u16x8 tv = *(const u16x8*)&Fl[row*296 + col];
      const int p0 = hh*288 + col;
      int ch2 = p0 / 9;
      int rr2 = p0 - ch2*9;
      const int l2 = l0 + row;
      const int h2 = l2 / 56;
      const int hb2 = (h2 - h0)*64 + (l2 - h2*56);
      u16x8 o;
      #pragma unroll
      for (int c2 = 0; c2 < 8; ++c2){
        const int di2 = (rr2 >= 3) + (rr2 >= 6);
        const int spat = hb2 + di2*64 + (rr2 - di2*3);
        const u16 av_ = xt2[spat*72 + (((ch2>>3) + 2*spat) & 7)*8 + (ch2 & 7)];
        o[c2] = f2bf(bits2f(tv[c2]) + bits2f(av_) * inv);
        const bool w9 = (rr2 == 8);
        rr2 = w9 ? 0 : rr2 + 1;
        ch2 += w9 ? 1 : 0;
      }
      *(u16x8*)(F + (size_t)(n0 + row)*P_ + hh*288 + col) = o;
    }
  }
}

// ---- K4: MFMA GEMM out = WbP * F (+bias). Double-buffered F staging, ------
// one barrier per K-step, loads issued a full iteration ahead.
__global__ __launch_bounds__(256) void k4_conv(const u16* __restrict__ F,
    const u16* __restrict__ WbP, const float* __restrict__ bias,
    float* __restrict__ out){
  __shared__ short Fl[2][128*40];   // 2 x 10 KB
  const int t = threadIdx.x;
  const int lane = t & 63;
  const int w = t >> 6;
  const int wn = w >> 1;
  const int ws = w & 1;
  const int g  = lane >> 4;
  const int lr = lane & 15;
  const int b  = blockIdx.y;
  const int s0 = blockIdx.x * 128;
  const u16* Fb = F + (size_t)b * ((size_t)P_ * L_);

  // staging coords: e=0 -> sch, e=1 -> sch+8 (c = t + e*256, ql = c&31)
  const int ql  = t & 31;
  const int sch = t >> 5;                 // 0..7
  const int sb0 = s0 + sch*8;
  const int sb1 = s0 + (sch + 8)*8;
  const int sc0 = (sb0 < L_ - 8) ? sb0 : (L_ - 8);
  const int sc1 = (sb1 < L_ - 8) ? sb1 : (L_ - 8);
  const int r00 = sb0 % 56;
  const int r01 = sb1 % 56;

  f32x4 acc[4][4];
  #pragma unroll
  for (int i = 0; i < 4; ++i)
    #pragma unroll
    for (int j = 0; j < 4; ++j) acc[i][j] = (f32x4){0.f,0.f,0.f,0.f};

  u16x8 vv0, vv1;
  // prologue: load step 0, write Fl[0], load step 1
  {
    vv0 = *(const u16x8*)(Fb + (size_t)(0*32 + ql)*L_ + sc0);
    vv1 = *(const u16x8*)(Fb + (size_t)(0*32 + ql)*L_ + sc1);
    const int q = ql;
    const int q3 = q/3;
    const bool kx0 = (q - q3*3) == 0;
    const bool ky0 = (q3 % 3) == 0;
    #pragma unroll
    for (int u = 0; u < 8; ++u){
      const bool m0a = ky0 && (sb0 + u) < 56;
      const bool m1a = kx0 && ((r00 + u) == 0 || (r00 + u) == 56);
      Fl[0][(sch*8 + u)*40 + ql] = (m0a || m1a) ? (short)0 : (short)vv0[u];
      const bool m0b = ky0 && (sb1 + u) < 56;
      const bool m1b = kx0 && ((r01 + u) == 0 || (r01 + u) == 56);
      Fl[0][((sch+8)*8 + u)*40 + ql] = (m0b || m1b) ? (short)0 : (short)vv1[u];
    }
    vv0 = *(const u16x8*)(Fb + (size_t)(1*32 + ql)*L_ + sc0);
    vv1 = *(const u16x8*)(Fb + (size_t)(1*32 + ql)*L_ + sc1);
  }
  __syncthreads();

  for (int step = 0; step < 18; ++step){
    // MFMA from Fl[step&1]
    const short* cur = Fl[step & 1];
    bf16x8 af[4], bb[4];
    #pragma unroll
    for (int i = 0; i < 4; ++i)
      af[i] = *(const bf16x8*)(WbP + (((size_t)(wn*4 + i)*18 + step)*64 + lane)*8);
    #pragma unroll
    for (int j = 0; j < 4; ++j)
      bb[j] = *(const bf16x8*)&cur[(ws*64 + j*16 + lr)*40 + g*8];
    #pragma unroll
    for (int i = 0; i < 4; ++i)
      #pragma unroll
      for (int j = 0; j < 4; ++j)
        acc[i][j] = __builtin_amdgcn_mfma_f32_16x16x32_bf16(af[i], bb[j], acc[i][j], 0, 0, 0);

    // write step+1 (regs loaded last iteration), then load step+2
    if (step + 1 < 18){
      short* nxt = Fl[(step + 1) & 1];
      const int q = (step + 1)*32 + ql;
      const int q3 = q/3;
      const bool kx0 = (q - q3*3) == 0;
      const bool ky0 = (q3 % 3) == 0;
      #pragma unroll
      for (int u = 0; u < 8; ++u){
        const bool m0a = ky0 && (sb0 + u) < 56;
        const bool m1a = kx0 && ((r00 + u) == 0 || (r00 + u) == 56);
        nxt[(sch*8 + u)*40 + ql] = (m0a || m1a) ? (short)0 : (short)vv0[u];
        const bool m0b = ky0 && (sb1 + u) < 56;
        const bool m1b = kx0 && ((r01 + u) == 0 || (r01 + u) == 56);
        nxt[((sch+8)*8 + u)*40 + ql] = (m0b || m1b) ? (short)0 : (short)vv1[u];
      }
      if (step + 2 < 18){
        vv0 = *(const u16x8*)(Fb + (size_t)((step+2)*32 + ql)*L_ + sc0);
        vv1 = *(const u16x8*)(Fb + (size_t)((step+2)*32 + ql)*L_ + sc1);
      }
    }
    __syncthreads();
  }

  #pragma unroll
  for (int i = 0; i < 4; ++i)
    #pragma unroll
    for (int r = 0; r < 4; ++r){
      const int co = wn*64 + i*16 + g*4 + r;
      const float bv = bias[co];
      #pragma unroll
      for (int j = 0; j < 4; ++j){
        const int s = s0 + ws*64 + j*16 + lr;
        if (s < L_) out[((size_t)b*COUT + co)*L_ + s] = acc[i][j][r] + bv;
      }
    }
}

extern "C" void kernel_launch(void* const* d_in, const int* in_sizes, int n_in,
                              void* d_out, int out_size, void* d_ws, size_t ws_size,
                              hipStream_t stream){
  const float* x      = (const float*)d_in[0];
  const float* weight = (const float*)d_in[1];
  const float* bias   = (const float*)d_in[2];
  const float* cc     = (const float*)d_in[3];
  const float* temp_p = (const float*)d_in[4];
  float* out = (float*)d_out;

  char* ws = (char*)d_ws;
  u16*   F   = (u16*)(ws);                 // 115,605,504 B (standard [n][p])
  float* b2v = (float*)(ws + 115605504);   //       1,024 B
  u16*   CbP = (u16*)(ws + 115606528);     //     294,912 B
  u16*   CtP = (u16*)(ws + 115901440);     //     294,912 B
  u16*   WbP = (u16*)(ws + 116196352);     //     147,456 B

  k0_prep <<<436,          256, 0, stream>>>(cc, weight, CbP, CtP, b2v, WbP);
  k123    <<<N_/64,        512, 0, stream>>>(x, CbP, CtP, b2v, temp_p, F);
  k4_conv <<<dim3(25, B_), 256, 0, stream>>>(F, WbP, bias, out);
}

// Round 22
// 202.666 us; speedup vs baseline: 1.3723x; 1.0577x over previous
//
#include <hip/hip_runtime.h>
#include <hip/hip_bf16.h>

#define B_    32
#define CIN   64
#define HW    56
#define COUT  128
#define M_    256
#define P_    576
#define L_    3136
#define N_    100352

typedef __hip_bfloat16 bf16;
typedef unsigned short u16;
typedef __attribute__((ext_vector_type(2))) unsigned short u16x2;
typedef __attribute__((ext_vector_type(8))) short bf16x8;
typedef __attribute__((ext_vector_type(8))) unsigned short u16x8;
typedef __attribute__((ext_vector_type(4))) float f32x4;

__device__ __forceinline__ float bits2f(u16 u){ return __uint_as_float(((unsigned)u) << 16); }
__device__ __forceinline__ u16 f2bf(float f){
  bf16 h = __float2bfloat16(f);
  return *(u16*)&h;
}

// ---- K0: fragment-major operand layouts + b2 -------------------------------
__global__ __launch_bounds__(256) void k0_prep(const float* __restrict__ C,
                                               const float* __restrict__ W,
                                               u16* __restrict__ CbP, u16* __restrict__ CtP,
                                               float* __restrict__ b2v, u16* __restrict__ WbP){
  __shared__ float red[4];
  const int t = threadIdx.x;
  const int bid = blockIdx.x;
  if (bid < M_){
    const int m = bid;
    float s = 0.f;
    for (int p = t; p < P_; p += 256){
      float vr = bits2f(f2bf(C[(size_t)m*P_ + p]));
      s += vr*vr;
    }
    #pragma unroll
    for (int off = 32; off >= 1; off >>= 1) s += __shfl_xor(s, off);
    if ((t & 63) == 0) red[t >> 6] = s;
    __syncthreads();
    if (t == 0) b2v[m] = red[0] + red[1] + red[2] + red[3];
  } else if (bid < M_ + 72){
    const int u = (bid - M_)*256 + t;
    const int f = u >> 6, lane = u & 63;
    const int g = lane >> 4, lr = lane & 15;
    const int k = f % 18, fj = f / 18;
    const int j = fj & 3, wvq = fj >> 2;
    const int m = wvq*64 + j*16 + lr;
    const int idx = k*4 + g;
    const int o = idx & 7, rr = idx >> 3;
    u16x8 o8;
    #pragma unroll
    for (int c = 0; c < 8; ++c) o8[c] = f2bf(C[(size_t)m*P_ + (o*8 + c)*9 + rr]);
    *(u16x8*)&CbP[(size_t)u*8] = o8;
  } else if (bid < M_ + 144){
    const int u = (bid - M_ - 72)*256 + t;
    const int f = u >> 6, lane = u & 63;
    const int g = lane >> 4, lr = lane & 15;
    const int mc = f & 7, fj = f >> 3;
    const int j = fj % 9, q = fj / 9;
    const int p = q*144 + j*16 + lr;
    const int m = mc*32 + g*8;
    u16x8 o8;
    #pragma unroll
    for (int c = 0; c < 8; ++c) o8[c] = f2bf(C[(size_t)(m + c)*P_ + p]);
    *(u16x8*)&CtP[(size_t)u*8] = o8;
  } else {
    const int u = (bid - M_ - 144)*256 + t;
    const int f = u >> 6, lane = u & 63;
    const int g = lane >> 4, lr = lane & 15;
    const int k = f % 18, fi = f / 18;
    const int i = fi & 3, wn = fi >> 2;
    const int co = wn*64 + i*16 + lr;
    const int q = k*32 + g*8;
    u16x8 o8;
    #pragma unroll
    for (int c = 0; c < 8; ++c) o8[c] = f2bf(W[(size_t)co*P_ + q + c]);
    *(u16x8*)&WbP[(size_t)u*8] = o8;
  }
}

// ---- K123: fused unfold+assign+transform. 512 threads, 8 waves. ------------
// wv = ih*4+mq. XCD-aware block swizzle (nwg = 1568 = 8*196, bijective).
__global__ __launch_bounds__(512, 4) void k123(const float* __restrict__ x,
    const u16* __restrict__ CbP, const u16* __restrict__ CtP,
    const float* __restrict__ b2v, const float* __restrict__ temp_p,
    u16* __restrict__ F){
  __shared__ __align__(16) char lds[76288];
  u16*   xt2 = (u16*)lds;                 // 256 spat x 72 u16 = 36864 B
  char*  Bz  = lds + 36864;               // 37888 B overlay: Sl / Fl
  u16*   Sl  = (u16*)Bz;                  // 64 x 264 u16 = 33792 B
  u16*   Fl  = (u16*)Bz;                  // 64 x 296 u16 = 37888 B
  float* a2l = (float*)(lds + 74752);     // 2 x 64 f (partials by ih)
  float* red = (float*)(lds + 75264);     // 256 f

  const int t = threadIdx.x;
  const int lane = t & 63;
  const int wv = t >> 6;                  // 0..7
  const int ih = wv >> 2;                 // row half
  const int mq = wv & 3;                  // m/p quarter
  const int g  = lane >> 4;
  const int lr = lane & 15;
  const int blk_raw = blockIdx.x;
  const int blk = (blk_raw & 7) * 196 + (blk_raw >> 3);   // XCD-chunked
  const int n0 = blk * 64;
  const int b  = n0 / L_;
  const int l0 = n0 - b * L_;
  const int h0 = l0 / 56;
  const float temp = *temp_p;

  // ---- stage x window transposed (channel-pair vectorized writes) ----
  const float* xb = x + (size_t)b * CIN * L_;
  {
    const int wc = t & 63;
    const int ix = wc - 1;
    const bool okx = (unsigned)ix < 56u;
    #pragma unroll 4
    for (int iter = 0; iter < 16; ++iter){
      const int idx = (t >> 6) + iter*8;   // 0..127 (channel-pair, ry)
      const int cp  = idx & 31;            // channel pair
      const int ry  = idx >> 5;            // 0..3
      const int c0  = cp*2;
      const int iy = h0 - 1 + ry;
      float v0 = 0.f, v1 = 0.f;
      if ((unsigned)iy < 56u && okx){
        v0 = xb[(size_t)c0*L_ + iy*56 + ix];
        v1 = xb[(size_t)(c0+1)*L_ + iy*56 + ix];
      }
      const int spat = ry*64 + wc;
      u16x2 o = { f2bf(v0), f2bf(v1) };
      *(u16x2*)&xt2[spat*72 + (((c0>>3) + 2*spat) & 7)*8 + (c0 & 7)] = o;
    }
  }
  __syncthreads();

  // ---- a2 partials: row = mq*16+lr; ih splits the 18 z-steps ----
  {
    const int l_  = l0 + mq*16 + lr;
    const int hwB = (l_/56 - h0)*64 + (l_ - (l_/56)*56);
    float s2 = 0.f;
    #pragma unroll
    for (int z = 0; z < 9; ++z){
      const int uu = (ih*9 + z)*4 + g;
      const int rr = uu >> 3, o = uu & 7;
      const int di = (rr >= 3) + (rr >= 6);
      const int spat = hwB + di*64 + (rr - di*3);
      u16x8 v8 = *(const u16x8*)&xt2[spat*72 + ((o + 2*spat) & 7)*8];
      #pragma unroll
      for (int c = 0; c < 8; ++c){
        const float vr = bits2f(v8[c]);
        s2 = fmaf(vr, vr, s2);
      }
    }
    s2 += __shfl_xor(s2, 16);
    s2 += __shfl_xor(s2, 32);
    if (g == 0) a2l[ih*64 + mq*16 + lr] = s2;
  }
  __syncthreads();               // a2l visible

  // ================= phase 1: G = A * Cb^T (no barriers) =================
  int hw2[2];
  #pragma unroll
  for (int i = 0; i < 2; ++i){
    const int li = l0 + ih*32 + i*16 + lr;
    const int hi = li / 56;
    hw2[i] = (hi - h0)*64 + (li - hi*56);
  }

  f32x4 acc[2][4];
  #pragma unroll
  for (int i = 0; i < 2; ++i)
    #pragma unroll
    for (int j = 0; j < 4; ++j) acc[i][j] = (f32x4){0.f,0.f,0.f,0.f};

  bf16x8 bbc[4], bbn[4];
  #pragma unroll
  for (int j = 0; j < 4; ++j)
    bbc[j] = *(const bf16x8*)(CbP + (((size_t)(mq*4 + j)*18 + 0)*64 + lane)*8);

  #pragma unroll
  for (int kk = 0; kk < 18; ++kk){
    const int idx = kk*4 + g;
    const int rr = idx >> 3, o = idx & 7;
    const int di = (rr >= 3) + (rr >= 6);
    const int doff = di*64 + (rr - di*3);
    bf16x8 af[2];
    #pragma unroll
    for (int i = 0; i < 2; ++i){
      const int spat = hw2[i] + doff;
      af[i] = *(const bf16x8*)&xt2[spat*72 + ((o + 2*spat) & 7)*8];
    }
    if (kk + 1 < 18){
      #pragma unroll
      for (int j = 0; j < 4; ++j)
        bbn[j] = *(const bf16x8*)(CbP + (((size_t)(mq*4 + j)*18 + (kk+1))*64 + lane)*8);
    }
    #pragma unroll
    for (int i = 0; i < 2; ++i)
      #pragma unroll
      for (int j = 0; j < 4; ++j)
        acc[i][j] = __builtin_amdgcn_mfma_f32_16x16x32_bf16(af[i], bbc[j], acc[i][j], 0, 0, 0);
    if (kk + 1 < 18){
      #pragma unroll
      for (int j = 0; j < 4; ++j) bbc[j] = bbn[j];
    }
  }

  // ---- softmax over all 256 m (rows split by ih, cols by mq) ----
  float a2r[2][4], b2r[4];
  #pragma unroll
  for (int i = 0; i < 2; ++i)
    #pragma unroll
    for (int r = 0; r < 4; ++r){
      const int row = ih*32 + i*16 + g*4 + r;
      a2r[i][r] = a2l[row] + a2l[64 + row];
    }
  #pragma unroll
  for (int j = 0; j < 4; ++j) b2r[j] = b2v[mq*64 + j*16 + lr];

  float rmax[2][4];
  #pragma unroll
  for (int i = 0; i < 2; ++i)
    #pragma unroll
    for (int r = 0; r < 4; ++r) rmax[i][r] = -3.4e38f;

  #pragma unroll
  for (int i = 0; i < 2; ++i)
    #pragma unroll
    for (int j = 0; j < 4; ++j)
      #pragma unroll
      for (int r = 0; r < 4; ++r){
        float d2 = fmaxf(a2r[i][r] + b2r[j] - 2.f*acc[i][j][r], 1e-12f);
        float lg = -temp * sqrtf(d2);
        acc[i][j][r] = lg;
        rmax[i][r] = fmaxf(rmax[i][r], lg);
      }
  #pragma unroll
  for (int i = 0; i < 2; ++i)
    #pragma unroll
    for (int r = 0; r < 4; ++r){
      float v = rmax[i][r];
      v = fmaxf(v, __shfl_xor(v, 1));
      v = fmaxf(v, __shfl_xor(v, 2));
      v = fmaxf(v, __shfl_xor(v, 4));
      v = fmaxf(v, __shfl_xor(v, 8));
      rmax[i][r] = v;
    }
  __syncthreads();
  if (lr == 0){
    #pragma unroll
    for (int i = 0; i < 2; ++i)
      #pragma unroll
      for (int r = 0; r < 4; ++r)
        red[mq*64 + ih*32 + i*16 + g*4 + r] = rmax[i][r];
  }
  __syncthreads();
  #pragma unroll
  for (int i = 0; i < 2; ++i)
    #pragma unroll
    for (int r = 0; r < 4; ++r){
      const int row = ih*32 + i*16 + g*4 + r;
      rmax[i][r] = fmaxf(fmaxf(red[row], red[64+row]), fmaxf(red[128+row], red[192+row]));
    }
  float rsum[2][4];
  #pragma unroll
  for (int i = 0; i < 2; ++i)
    #pragma unroll
    for (int r = 0; r < 4; ++r) rsum[i][r] = 0.f;
  #pragma unroll
  for (int i = 0; i < 2; ++i)
    #pragma unroll
    for (int j = 0; j < 4; ++j)
      #pragma unroll
      for (int r = 0; r < 4; ++r){
        float pe = __expf(acc[i][j][r] - rmax[i][r]);
        acc[i][j][r] = pe;
        rsum[i][r] += pe;
      }
  #pragma unroll
  for (int i = 0; i < 2; ++i)
    #pragma unroll
    for (int r = 0; r < 4; ++r){
      float v = rsum[i][r];
      v += __shfl_xor(v, 1);
      v += __shfl_xor(v, 2);
      v += __shfl_xor(v, 4);
      v += __shfl_xor(v, 8);
      rsum[i][r] = v;
    }
  __syncthreads();
  if (lr == 0){
    #pragma unroll
    for (int i = 0; i < 2; ++i)
      #pragma unroll
      for (int r = 0; r < 4; ++r)
        red[mq*64 + ih*32 + i*16 + g*4 + r] = rsum[i][r];
  }
  __syncthreads();
  #pragma unroll
  for (int i = 0; i < 2; ++i)
    #pragma unroll
    for (int r = 0; r < 4; ++r){
      const int row = ih*32 + i*16 + g*4 + r;
      const float invr = 1.f / (red[row] + red[64+row] + red[128+row] + red[192+row]);
      #pragma unroll
      for (int j = 0; j < 4; ++j)
        Sl[(size_t)row*264 + mq*64 + j*16 + lr] = f2bf(acc[i][j][r] * invr);
    }
  __syncthreads();                 // Sl visible

  // ========== phase 2: T = Sl * Ct (no barriers, batch frag loads) ==========
  f32x4 acc2[2][9];
  #pragma unroll
  for (int i = 0; i < 2; ++i)
    #pragma unroll
    for (int j = 0; j < 9; ++j) acc2[i][j] = (f32x4){0.f,0.f,0.f,0.f};

  for (int mc = 0; mc < 8; ++mc){
    bf16x8 af2[2], bb2[9];
    #pragma unroll
    for (int i = 0; i < 2; ++i)
      af2[i] = *(const bf16x8*)&Sl[(size_t)(ih*32 + i*16 + lr)*264 + mc*32 + g*8];
    #pragma unroll
    for (int j = 0; j < 9; ++j)
      bb2[j] = *(const bf16x8*)(CtP + (((size_t)(mq*9 + j)*8 + mc)*64 + lane)*8);
    #pragma unroll
    for (int j = 0; j < 9; ++j)
      #pragma unroll
      for (int i = 0; i < 2; ++i)
        acc2[i][j] = __builtin_amdgcn_mfma_f32_16x16x32_bf16(af2[i], bb2[j], acc2[i][j], 0, 0, 0);
  }

  // ---- F write: two 288-p halves; skip term re-gathered from xt2 ----------
  const float inv = 1.f / (temp + 1.f);
  const float tscale = temp * inv;
  #pragma unroll
  for (int hh = 0; hh < 2; ++hh){
    __syncthreads();               // Fl region free
    if ((mq >> 1) == hh){
      const int pbase = (mq & 1) * 144;
      #pragma unroll
      for (int i = 0; i < 2; ++i)
        #pragma unroll
        for (int j = 0; j < 9; ++j)
          #pragma unroll
          for (int r = 0; r < 4; ++r)
            Fl[(ih*32 + i*16 + g*4 + r)*296 + pbase + j*16 + lr] = f2bf(acc2[i][j][r] * tscale);
    }
    __syncthreads();
    #pragma unroll
    for (int e = 0; e < 5; ++e){
      const int v = t + e*512;
      if (e == 4 && t >= 256) break;       // 2304 = 4*512 + 256
      const int row = v / 36, col = (v - row*36) * 8;
      u16x8 tv = *(const u16x8*)&Fl[row*296 + col];
      const int p0 = hh*288 + col;
      int ch2 = p0 / 9;
      int rr2 = p0 - ch2*9;
      const int l2 = l0 + row;
      const int h2 = l2 / 56;
      const int hb2 = (h2 - h0)*64 + (l2 - h2*56);
      u16x8 o;
      #pragma unroll
      for (int c2 = 0; c2 < 8; ++c2){
        const int di2 = (rr2 >= 3) + (rr2 >= 6);
        const int spat = hb2 + di2*64 + (rr2 - di2*3);
        const u16 av_ = xt2[spat*72 + (((ch2>>3) + 2*spat) & 7)*8 + (ch2 & 7)];
        o[c2] = f2bf(bits2f(tv[c2]) + bits2f(av_) * inv);
        const bool w9 = (rr2 == 8);
        rr2 = w9 ? 0 : rr2 + 1;
        ch2 += w9 ? 1 : 0;
      }
      *(u16x8*)(F + (size_t)(n0 + row)*P_ + hh*288 + col) = o;
    }
  }
}

// ---- K4: MFMA GEMM out = WbP * F (+bias). Double-buffered F staging. -------
__global__ __launch_bounds__(256) void k4_conv(const u16* __restrict__ F,
    const u16* __restrict__ WbP, const float* __restrict__ bias,
    float* __restrict__ out){
  __shared__ short Fl[2][128*40];   // 2 x 10 KB
  const int t = threadIdx.x;
  const int lane = t & 63;
  const int w = t >> 6;
  const int wn = w >> 1;
  const int ws = w & 1;
  const int g  = lane >> 4;
  const int lr = lane & 15;
  const int b  = blockIdx.y;
  const int s0 = blockIdx.x * 128;
  const u16* Fb = F + (size_t)b * ((size_t)P_ * L_);

  const int ql  = t & 31;
  const int sch = t >> 5;                 // 0..7
  const int sb0 = s0 + sch*8;
  const int sb1 = s0 + (sch + 8)*8;
  const int sc0 = (sb0 < L_ - 8) ? sb0 : (L_ - 8);
  const int sc1 = (sb1 < L_ - 8) ? sb1 : (L_ - 8);
  const int r00 = sb0 % 56;
  const int r01 = sb1 % 56;

  f32x4 acc[4][4];
  #pragma unroll
  for (int i = 0; i < 4; ++i)
    #pragma unroll
    for (int j = 0; j < 4; ++j) acc[i][j] = (f32x4){0.f,0.f,0.f,0.f};

  u16x8 vv0, vv1;
  {
    vv0 = *(const u16x8*)(Fb + (size_t)(0*32 + ql)*L_ + sc0);
    vv1 = *(const u16x8*)(Fb + (size_t)(0*32 + ql)*L_ + sc1);
    const int q = ql;
    const int q3 = q/3;
    const bool kx0 = (q - q3*3) == 0;
    const bool ky0 = (q3 % 3) == 0;
    #pragma unroll
    for (int u = 0; u < 8; ++u){
      const bool m0a = ky0 && (sb0 + u) < 56;
      const bool m1a = kx0 && ((r00 + u) == 0 || (r00 + u) == 56);
      Fl[0][(sch*8 + u)*40 + ql] = (m0a || m1a) ? (short)0 : (short)vv0[u];
      const bool m0b = ky0 && (sb1 + u) < 56;
      const bool m1b = kx0 && ((r01 + u) == 0 || (r01 + u) == 56);
      Fl[0][((sch+8)*8 + u)*40 + ql] = (m0b || m1b) ? (short)0 : (short)vv1[u];
    }
    vv0 = *(const u16x8*)(Fb + (size_t)(1*32 + ql)*L_ + sc0);
    vv1 = *(const u16x8*)(Fb + (size_t)(1*32 + ql)*L_ + sc1);
  }
  __syncthreads();

  for (int step = 0; step < 18; ++step){
    const short* cur = Fl[step & 1];
    bf16x8 af[4], bb[4];
    #pragma unroll
    for (int i = 0; i < 4; ++i)
      af[i] = *(const bf16x8*)(WbP + (((size_t)(wn*4 + i)*18 + step)*64 + lane)*8);
    #pragma unroll
    for (int j = 0; j < 4; ++j)
      bb[j] = *(const bf16x8*)&cur[(ws*64 + j*16 + lr)*40 + g*8];
    #pragma unroll
    for (int i = 0; i < 4; ++i)
      #pragma unroll
      for (int j = 0; j < 4; ++j)
        acc[i][j] = __builtin_amdgcn_mfma_f32_16x16x32_bf16(af[i], bb[j], acc[i][j], 0, 0, 0);

    if (step + 1 < 18){
      short* nxt = Fl[(step + 1) & 1];
      const int q = (step + 1)*32 + ql;
      const int q3 = q/3;
      const bool kx0 = (q - q3*3) == 0;
      const bool ky0 = (q3 % 3) == 0;
      #pragma unroll
      for (int u = 0; u < 8; ++u){
        const bool m0a = ky0 && (sb0 + u) < 56;
        const bool m1a = kx0 && ((r00 + u) == 0 || (r00 + u) == 56);
        nxt[(sch*8 + u)*40 + ql] = (m0a || m1a) ? (short)0 : (short)vv0[u];
        const bool m0b = ky0 && (sb1 + u) < 56;
        const bool m1b = kx0 && ((r01 + u) == 0 || (r01 + u) == 56);
        nxt[((sch+8)*8 + u)*40 + ql] = (m0b || m1b) ? (short)0 : (short)vv1[u];
      }
      if (step + 2 < 18){
        vv0 = *(const u16x8*)(Fb + (size_t)((step+2)*32 + ql)*L_ + sc0);
        vv1 = *(const u16x8*)(Fb + (size_t)((step+2)*32 + ql)*L_ + sc1);
      }
    }
    __syncthreads();
  }

  #pragma unroll
  for (int i = 0; i < 4; ++i)
    #pragma unroll
    for (int r = 0; r < 4; ++r){
      const int co = wn*64 + i*16 + g*4 + r;
      const float bv = bias[co];
      #pragma unroll
      for (int j = 0; j < 4; ++j){
        const int s = s0 + ws*64 + j*16 + lr;
        if (s < L_) out[((size_t)b*COUT + co)*L_ + s] = acc[i][j][r] + bv;
      }
    }
}

extern "C" void kernel_launch(void* const* d_in, const int* in_sizes, int n_in,
                              void* d_out, int out_size, void* d_ws, size_t ws_size,
                              hipStream_t stream){
  const float* x      = (const float*)d_in[0];
  const float* weight = (const float*)d_in[1];
  const float* bias   = (const float*)d_in[2];
  const float* cc     = (const float*)d_in[3];
  const float* temp_p = (const float*)d_in[4];
  float* out = (float*)d_out;

  char* ws = (char*)d_ws;
  u16*   F   = (u16*)(ws);                 // 115,605,504 B (standard [n][p])
  float* b2v = (float*)(ws + 115605504);   //       1,024 B
  u16*   CbP = (u16*)(ws + 115606528);     //     294,912 B
  u16*   CtP = (u16*)(ws + 115901440);     //     294,912 B
  u16*   WbP = (u16*)(ws + 116196352);     //     147,456 B

  k0_prep <<<436,          256, 0, stream>>>(cc, weight, CbP, CtP, b2v, WbP);
  k123    <<<N_/64,        512, 0, stream>>>(x, CbP, CtP, b2v, temp_p, F);
  k4_conv <<<dim3(25, B_), 256, 0, stream>>>(F, WbP, bias, out);
}

// Round 23
// 200.426 us; speedup vs baseline: 1.3877x; 1.0112x over previous
//
#include <hip/hip_runtime.h>
#include <hip/hip_bf16.h>

#define B_    32
#define CIN   64
#define HW    56
#define COUT  128
#define M_    256
#define P_    576
#define L_    3136
#define N_    100352

typedef __hip_bfloat16 bf16;
typedef unsigned short u16;
typedef __attribute__((ext_vector_type(2))) unsigned short u16x2;
typedef __attribute__((ext_vector_type(8))) short bf16x8;
typedef __attribute__((ext_vector_type(8))) unsigned short u16x8;
typedef __attribute__((ext_vector_type(4))) float f32x4;

__device__ __forceinline__ float bits2f(u16 u){ return __uint_as_float(((unsigned)u) << 16); }
__device__ __forceinline__ u16 f2bf(float f){
  bf16 h = __float2bfloat16(f);
  return *(u16*)&h;
}

// ---- K0: fragment-major operand layouts + b2 (b2 branch compacted) ---------
__global__ __launch_bounds__(256) void k0_prep(const float* __restrict__ C,
                                               const float* __restrict__ W,
                                               u16* __restrict__ CbP, u16* __restrict__ CtP,
                                               float* __restrict__ b2v, u16* __restrict__ WbP){
  const int t = threadIdx.x;
  const int bid = blockIdx.x;
  if (bid < 32){
    // 8 m per block; half-wave (32 lanes) per m
    const int m = bid*8 + (t >> 5);
    const int pl = t & 31;
    float s = 0.f;
    for (int it = 0; it < 18; ++it){
      const int p = pl + it*32;
      float vr = bits2f(f2bf(C[(size_t)m*P_ + p]));
      s += vr*vr;
    }
    #pragma unroll
    for (int off = 16; off >= 1; off >>= 1) s += __shfl_xor(s, off);
    if (pl == 0) b2v[m] = s;
  } else if (bid < 32 + 72){
    const int u = (bid - 32)*256 + t;
    const int f = u >> 6, lane = u & 63;
    const int g = lane >> 4, lr = lane & 15;
    const int k = f % 18, fj = f / 18;
    const int j = fj & 3, wvq = fj >> 2;
    const int m = wvq*64 + j*16 + lr;
    const int idx = k*4 + g;
    const int o = idx & 7, rr = idx >> 3;
    u16x8 o8;
    #pragma unroll
    for (int c = 0; c < 8; ++c) o8[c] = f2bf(C[(size_t)m*P_ + (o*8 + c)*9 + rr]);
    *(u16x8*)&CbP[(size_t)u*8] = o8;
  } else if (bid < 32 + 144){
    const int u = (bid - 32 - 72)*256 + t;
    const int f = u >> 6, lane = u & 63;
    const int g = lane >> 4, lr = lane & 15;
    const int mc = f & 7, fj = f >> 3;
    const int j = fj % 9, q = fj / 9;
    const int p = q*144 + j*16 + lr;
    const int m = mc*32 + g*8;
    u16x8 o8;
    #pragma unroll
    for (int c = 0; c < 8; ++c) o8[c] = f2bf(C[(size_t)(m + c)*P_ + p]);
    *(u16x8*)&CtP[(size_t)u*8] = o8;
  } else {
    const int u = (bid - 32 - 144)*256 + t;
    const int f = u >> 6, lane = u & 63;
    const int g = lane >> 4, lr = lane & 15;
    const int k = f % 18, fi = f / 18;
    const int i = fi & 3, wn = fi >> 2;
    const int co = wn*64 + i*16 + lr;
    const int q = k*32 + g*8;
    u16x8 o8;
    #pragma unroll
    for (int c = 0; c < 8; ++c) o8[c] = f2bf(W[(size_t)co*P_ + q + c]);
    *(u16x8*)&WbP[(size_t)u*8] = o8;
  }
}

// ---- K123: fused unfold+assign+transform. 512 threads, 8 waves. ------------
// wv = ih*4+mq. XCD-aware block swizzle (nwg = 1568 = 8*196, bijective).
__global__ __launch_bounds__(512, 4) void k123(const float* __restrict__ x,
    const u16* __restrict__ CbP, const u16* __restrict__ CtP,
    const float* __restrict__ b2v, const float* __restrict__ temp_p,
    u16* __restrict__ F){
  __shared__ __align__(16) char lds[76288];
  u16*   xt2 = (u16*)lds;                 // 256 spat x 72 u16 = 36864 B
  char*  Bz  = lds + 36864;               // 37888 B overlay: Sl / Fl
  u16*   Sl  = (u16*)Bz;                  // 64 x 264 u16 = 33792 B
  u16*   Fl  = (u16*)Bz;                  // 64 x 296 u16 = 37888 B
  float* a2l = (float*)(lds + 74752);     // 2 x 64 f (partials by ih)
  float* red = (float*)(lds + 75264);     // 256 f

  const int t = threadIdx.x;
  const int lane = t & 63;
  const int wv = t >> 6;                  // 0..7
  const int ih = wv >> 2;                 // row half
  const int mq = wv & 3;                  // m/p quarter
  const int g  = lane >> 4;
  const int lr = lane & 15;
  const int blk_raw = blockIdx.x;
  const int blk = (blk_raw & 7) * 196 + (blk_raw >> 3);   // XCD-chunked
  const int n0 = blk * 64;
  const int b  = n0 / L_;
  const int l0 = n0 - b * L_;
  const int h0 = l0 / 56;
  const float temp = *temp_p;

  // ---- stage x window transposed (channel-pair vectorized writes) ----
  const float* xb = x + (size_t)b * CIN * L_;
  {
    const int wc = t & 63;
    const int ix = wc - 1;
    const bool okx = (unsigned)ix < 56u;
    #pragma unroll 4
    for (int iter = 0; iter < 16; ++iter){
      const int idx = (t >> 6) + iter*8;   // 0..127 (channel-pair, ry)
      const int cp  = idx & 31;            // channel pair
      const int ry  = idx >> 5;            // 0..3
      const int c0  = cp*2;
      const int iy = h0 - 1 + ry;
      float v0 = 0.f, v1 = 0.f;
      if ((unsigned)iy < 56u && okx){
        v0 = xb[(size_t)c0*L_ + iy*56 + ix];
        v1 = xb[(size_t)(c0+1)*L_ + iy*56 + ix];
      }
      const int spat = ry*64 + wc;
      u16x2 o = { f2bf(v0), f2bf(v1) };
      *(u16x2*)&xt2[spat*72 + (((c0>>3) + 2*spat) & 7)*8 + (c0 & 7)] = o;
    }
  }
  __syncthreads();

  // ---- a2 partials: row = mq*16+lr; ih splits the 18 z-steps ----
  {
    const int l_  = l0 + mq*16 + lr;
    const int hwB = (l_/56 - h0)*64 + (l_ - (l_/56)*56);
    float s2 = 0.f;
    #pragma unroll
    for (int z = 0; z < 9; ++z){
      const int uu = (ih*9 + z)*4 + g;
      const int rr = uu >> 3, o = uu & 7;
      const int di = (rr >= 3) + (rr >= 6);
      const int spat = hwB + di*64 + (rr - di*3);
      u16x8 v8 = *(const u16x8*)&xt2[spat*72 + ((o + 2*spat) & 7)*8];
      #pragma unroll
      for (int c = 0; c < 8; ++c){
        const float vr = bits2f(v8[c]);
        s2 = fmaf(vr, vr, s2);
      }
    }
    s2 += __shfl_xor(s2, 16);
    s2 += __shfl_xor(s2, 32);
    if (g == 0) a2l[ih*64 + mq*16 + lr] = s2;
  }
  __syncthreads();               // a2l visible

  // ================= phase 1: G = A * Cb^T (no barriers) =================
  int hw2[2];
  #pragma unroll
  for (int i = 0; i < 2; ++i){
    const int li = l0 + ih*32 + i*16 + lr;
    const int hi = li / 56;
    hw2[i] = (hi - h0)*64 + (li - hi*56);
  }

  f32x4 acc[2][4];
  #pragma unroll
  for (int i = 0; i < 2; ++i)
    #pragma unroll
    for (int j = 0; j < 4; ++j) acc[i][j] = (f32x4){0.f,0.f,0.f,0.f};

  bf16x8 bbc[4], bbn[4];
  #pragma unroll
  for (int j = 0; j < 4; ++j)
    bbc[j] = *(const bf16x8*)(CbP + (((size_t)(mq*4 + j)*18 + 0)*64 + lane)*8);

  #pragma unroll
  for (int kk = 0; kk < 18; ++kk){
    const int idx = kk*4 + g;
    const int rr = idx >> 3, o = idx & 7;
    const int di = (rr >= 3) + (rr >= 6);
    const int doff = di*64 + (rr - di*3);
    bf16x8 af[2];
    #pragma unroll
    for (int i = 0; i < 2; ++i){
      const int spat = hw2[i] + doff;
      af[i] = *(const bf16x8*)&xt2[spat*72 + ((o + 2*spat) & 7)*8];
    }
    if (kk + 1 < 18){
      #pragma unroll
      for (int j = 0; j < 4; ++j)
        bbn[j] = *(const bf16x8*)(CbP + (((size_t)(mq*4 + j)*18 + (kk+1))*64 + lane)*8);
    }
    #pragma unroll
    for (int i = 0; i < 2; ++i)
      #pragma unroll
      for (int j = 0; j < 4; ++j)
        acc[i][j] = __builtin_amdgcn_mfma_f32_16x16x32_bf16(af[i], bbc[j], acc[i][j], 0, 0, 0);
    if (kk + 1 < 18){
      #pragma unroll
      for (int j = 0; j < 4; ++j) bbc[j] = bbn[j];
    }
  }

  // ---- softmax over all 256 m (rows split by ih, cols by mq) ----
  float a2r[2][4], b2r[4];
  #pragma unroll
  for (int i = 0; i < 2; ++i)
    #pragma unroll
    for (int r = 0; r < 4; ++r){
      const int row = ih*32 + i*16 + g*4 + r;
      a2r[i][r] = a2l[row] + a2l[64 + row];
    }
  #pragma unroll
  for (int j = 0; j < 4; ++j) b2r[j] = b2v[mq*64 + j*16 + lr];

  float rmax[2][4];
  #pragma unroll
  for (int i = 0; i < 2; ++i)
    #pragma unroll
    for (int r = 0; r < 4; ++r) rmax[i][r] = -3.4e38f;

  #pragma unroll
  for (int i = 0; i < 2; ++i)
    #pragma unroll
    for (int j = 0; j < 4; ++j)
      #pragma unroll
      for (int r = 0; r < 4; ++r){
        float d2 = fmaxf(a2r[i][r] + b2r[j] - 2.f*acc[i][j][r], 1e-12f);
        float lg = -temp * sqrtf(d2);
        acc[i][j][r] = lg;
        rmax[i][r] = fmaxf(rmax[i][r], lg);
      }
  #pragma unroll
  for (int i = 0; i < 2; ++i)
    #pragma unroll
    for (int r = 0; r < 4; ++r){
      float v = rmax[i][r];
      v = fmaxf(v, __shfl_xor(v, 1));
      v = fmaxf(v, __shfl_xor(v, 2));
      v = fmaxf(v, __shfl_xor(v, 4));
      v = fmaxf(v, __shfl_xor(v, 8));
      rmax[i][r] = v;
    }
  __syncthreads();
  if (lr == 0){
    #pragma unroll
    for (int i = 0; i < 2; ++i)
      #pragma unroll
      for (int r = 0; r < 4; ++r)
        red[mq*64 + ih*32 + i*16 + g*4 + r] = rmax[i][r];
  }
  __syncthreads();
  #pragma unroll
  for (int i = 0; i < 2; ++i)
    #pragma unroll
    for (int r = 0; r < 4; ++r){
      const int row = ih*32 + i*16 + g*4 + r;
      rmax[i][r] = fmaxf(fmaxf(red[row], red[64+row]), fmaxf(red[128+row], red[192+row]));
    }
  float rsum[2][4];
  #pragma unroll
  for (int i = 0; i < 2; ++i)
    #pragma unroll
    for (int r = 0; r < 4; ++r) rsum[i][r] = 0.f;
  #pragma unroll
  for (int i = 0; i < 2; ++i)
    #pragma unroll
    for (int j = 0; j < 4; ++j)
      #pragma unroll
      for (int r = 0; r < 4; ++r){
        float pe = __expf(acc[i][j][r] - rmax[i][r]);
        acc[i][j][r] = pe;
        rsum[i][r] += pe;
      }
  #pragma unroll
  for (int i = 0; i < 2; ++i)
    #pragma unroll
    for (int r = 0; r < 4; ++r){
      float v = rsum[i][r];
      v += __shfl_xor(v, 1);
      v += __shfl_xor(v, 2);
      v += __shfl_xor(v, 4);
      v += __shfl_xor(v, 8);
      rsum[i][r] = v;
    }
  __syncthreads();
  if (lr == 0){
    #pragma unroll
    for (int i = 0; i < 2; ++i)
      #pragma unroll
      for (int r = 0; r < 4; ++r)
        red[mq*64 + ih*32 + i*16 + g*4 + r] = rsum[i][r];
  }
  __syncthreads();
  #pragma unroll
  for (int i = 0; i < 2; ++i)
    #pragma unroll
    for (int r = 0; r < 4; ++r){
      const int row = ih*32 + i*16 + g*4 + r;
      const float invr = 1.f / (red[row] + red[64+row] + red[128+row] + red[192+row]);
      #pragma unroll
      for (int j = 0; j < 4; ++j)
        Sl[(size_t)row*264 + mq*64 + j*16 + lr] = f2bf(acc[i][j][r] * invr);
    }
  __syncthreads();                 // Sl visible

  // ========== phase 2: T = Sl * Ct (no barriers, batch frag loads) ==========
  f32x4 acc2[2][9];
  #pragma unroll
  for (int i = 0; i < 2; ++i)
    #pragma unroll
    for (int j = 0; j < 9; ++j) acc2[i][j] = (f32x4){0.f,0.f,0.f,0.f};

  for (int mc = 0; mc < 8; ++mc){
    bf16x8 af2[2], bb2[9];
    #pragma unroll
    for (int i = 0; i < 2; ++i)
      af2[i] = *(const bf16x8*)&Sl[(size_t)(ih*32 + i*16 + lr)*264 + mc*32 + g*8];
    #pragma unroll
    for (int j = 0; j < 9; ++j)
      bb2[j] = *(const bf16x8*)(CtP + (((size_t)(mq*9 + j)*8 + mc)*64 + lane)*8);
    #pragma unroll
    for (int j = 0; j < 9; ++j)
      #pragma unroll
      for (int i = 0; i < 2; ++i)
        acc2[i][j] = __builtin_amdgcn_mfma_f32_16x16x32_bf16(af2[i], bb2[j], acc2[i][j], 0, 0, 0);
  }

  // ---- F write: two 288-p halves; skip gather via magic-div (chain-free) ---
  const float inv = 1.f / (temp + 1.f);
  const float tscale = temp * inv;
  #pragma unroll
  for (int hh = 0; hh < 2; ++hh){
    __syncthreads();               // Fl region free
    if ((mq >> 1) == hh){
      const int pbase = (mq & 1) * 144;
      #pragma unroll
      for (int i = 0; i < 2; ++i)
        #pragma unroll
        for (int j = 0; j < 9; ++j)
          #pragma unroll
          for (int r = 0; r < 4; ++r)
            Fl[(ih*32 + i*16 + g*4 + r)*296 + pbase + j*16 + lr] = f2bf(acc2[i][j][r] * tscale);
    }
    __syncthreads();
    #pragma unroll
    for (int e = 0; e < 5; ++e){
      if (e == 4 && t >= 256) break;       // 2304 = 4*512 + 256
      const int v = t + e*512;
      const int row = v / 36, col = (v - row*36) * 8;
      u16x8 tv = *(const u16x8*)&Fl[row*296 + col];
      const int p0 = hh*288 + col;
      const int l2 = l0 + row;
      const int h2 = l2 / 56;
      const int hb2 = (h2 - h0)*64 + (l2 - h2*56);
      u16x8 o;
      #pragma unroll
      for (int c2 = 0; c2 < 8; ++c2){
        const int p  = p0 + c2;
        const int ch = (p * 7282) >> 16;   // exact p/9 for p < 3640*9
        const int rr = p - ch*9;
        const int di = (rr >= 3) + (rr >= 6);
        const int spat = hb2 + di*64 + (rr - di*3);
        const u16 av_ = xt2[spat*72 + (((ch>>3) + 2*spat) & 7)*8 + (ch & 7)];
        o[c2] = f2bf(bits2f(tv[c2]) + bits2f(av_) * inv);
      }
      *(u16x8*)(F + (size_t)(n0 + row)*P_ + hh*288 + col) = o;
    }
  }
}

// ---- K4: MFMA GEMM out = WbP * F (+bias). Double-buffered F staging. -------
__global__ __launch_bounds__(256) void k4_conv(const u16* __restrict__ F,
    const u16* __restrict__ WbP, const float* __restrict__ bias,
    float* __restrict__ out){
  __shared__ short Fl[2][128*40];   // 2 x 10 KB
  const int t = threadIdx.x;
  const int lane = t & 63;
  const int w = t >> 6;
  const int wn = w >> 1;
  const int ws = w & 1;
  const int g  = lane >> 4;
  const int lr = lane & 15;
  const int b  = blockIdx.y;
  const int s0 = blockIdx.x * 128;
  const u16* Fb = F + (size_t)b * ((size_t)P_ * L_);

  const int ql  = t & 31;
  const int sch = t >> 5;                 // 0..7
  const int sb0 = s0 + sch*8;
  const int sb1 = s0 + (sch + 8)*8;
  const int sc0 = (sb0 < L_ - 8) ? sb0 : (L_ - 8);
  const int sc1 = (sb1 < L_ - 8) ? sb1 : (L_ - 8);
  const int r00 = sb0 % 56;
  const int r01 = sb1 % 56;

  f32x4 acc[4][4];
  #pragma unroll
  for (int i = 0; i < 4; ++i)
    #pragma unroll
    for (int j = 0; j < 4; ++j) acc[i][j] = (f32x4){0.f,0.f,0.f,0.f};

  u16x8 vv0, vv1;
  {
    vv0 = *(const u16x8*)(Fb + (size_t)(0*32 + ql)*L_ + sc0);
    vv1 = *(const u16x8*)(Fb + (size_t)(0*32 + ql)*L_ + sc1);
    const int q = ql;
    const int q3 = q/3;
    const bool kx0 = (q - q3*3) == 0;
    const bool ky0 = (q3 % 3) == 0;
    #pragma unroll
    for (int u = 0; u < 8; ++u){
      const bool m0a = ky0 && (sb0 + u) < 56;
      const bool m1a = kx0 && ((r00 + u) == 0 || (r00 + u) == 56);
      Fl[0][(sch*8 + u)*40 + ql] = (m0a || m1a) ? (short)0 : (short)vv0[u];
      const bool m0b = ky0 && (sb1 + u) < 56;
      const bool m1b = kx0 && ((r01 + u) == 0 || (r01 + u) == 56);
      Fl[0][((sch+8)*8 + u)*40 + ql] = (m0b || m1b) ? (short)0 : (short)vv1[u];
    }
    vv0 = *(const u16x8*)(Fb + (size_t)(1*32 + ql)*L_ + sc0);
    vv1 = *(const u16x8*)(Fb + (size_t)(1*32 + ql)*L_ + sc1);
  }
  __syncthreads();

  for (int step = 0; step < 18; ++step){
    const short* cur = Fl[step & 1];
    bf16x8 af[4], bb[4];
    #pragma unroll
    for (int i = 0; i < 4; ++i)
      af[i] = *(const bf16x8*)(WbP + (((size_t)(wn*4 + i)*18 + step)*64 + lane)*8);
    #pragma unroll
    for (int j = 0; j < 4; ++j)
      bb[j] = *(const bf16x8*)&cur[(ws*64 + j*16 + lr)*40 + g*8];
    #pragma unroll
    for (int i = 0; i < 4; ++i)
      #pragma unroll
      for (int j = 0; j < 4; ++j)
        acc[i][j] = __builtin_amdgcn_mfma_f32_16x16x32_bf16(af[i], bb[j], acc[i][j], 0, 0, 0);

    if (step + 1 < 18){
      short* nxt = Fl[(step + 1) & 1];
      const int q = (step + 1)*32 + ql;
      const int q3 = q/3;
      const bool kx0 = (q - q3*3) == 0;
      const bool ky0 = (q3 % 3) == 0;
      #pragma unroll
      for (int u = 0; u < 8; ++u){
        const bool m0a = ky0 && (sb0 + u) < 56;
        const bool m1a = kx0 && ((r00 + u) == 0 || (r00 + u) == 56);
        nxt[(sch*8 + u)*40 + ql] = (m0a || m1a) ? (short)0 : (short)vv0[u];
        const bool m0b = ky0 && (sb1 + u) < 56;
        const bool m1b = kx0 && ((r01 + u) == 0 || (r01 + u) == 56);
        nxt[((sch+8)*8 + u)*40 + ql] = (m0b || m1b) ? (short)0 : (short)vv1[u];
      }
      if (step + 2 < 18){
        vv0 = *(const u16x8*)(Fb + (size_t)((step+2)*32 + ql)*L_ + sc0);
        vv1 = *(const u16x8*)(Fb + (size_t)((step+2)*32 + ql)*L_ + sc1);
      }
    }
    __syncthreads();
  }

  #pragma unroll
  for (int i = 0; i < 4; ++i)
    #pragma unroll
    for (int r = 0; r < 4; ++r){
      const int co = wn*64 + i*16 + g*4 + r;
      const float bv = bias[co];
      #pragma unroll
      for (int j = 0; j < 4; ++j){
        const int s = s0 + ws*64 + j*16 + lr;
        if (s < L_) out[((size_t)b*COUT + co)*L_ + s] = acc[i][j][r] + bv;
      }
    }
}

extern "C" void kernel_launch(void* const* d_in, const int* in_sizes, int n_in,
                              void* d_out, int out_size, void* d_ws, size_t ws_size,
                              hipStream_t stream){
  const float* x      = (const float*)d_in[0];
  const float* weight = (const float*)d_in[1];
  const float* bias   = (const float*)d_in[2];
  const float* cc     = (const float*)d_in[3];
  const float* temp_p = (const float*)d_in[4];
  float* out = (float*)d_out;

  char* ws = (char*)d_ws;
  u16*   F   = (u16*)(ws);                 // 115,605,504 B (standard [n][p])
  float* b2v = (float*)(ws + 115605504);   //       1,024 B
  u16*   CbP = (u16*)(ws + 115606528);     //     294,912 B
  u16*   CtP = (u16*)(ws + 115901440);     //     294,912 B
  u16*   WbP = (u16*)(ws + 116196352);     //     147,456 B

  k0_prep <<<212,          256, 0, stream>>>(cc, weight, CbP, CtP, b2v, WbP);
  k123    <<<N_/64,        512, 0, stream>>>(x, CbP, CtP, b2v, temp_p, F);
  k4_conv <<<dim3(25, B_), 256, 0, stream>>>(F, WbP, bias, out);
}

// Round 24
// 198.945 us; speedup vs baseline: 1.3980x; 1.0074x over previous
//
#include <hip/hip_runtime.h>
#include <hip/hip_bf16.h>

#define B_    32
#define CIN   64
#define HW    56
#define COUT  128
#define M_    256
#define P_    576
#define L_    3136
#define N_    100352

typedef __hip_bfloat16 bf16;
typedef unsigned short u16;
typedef __attribute__((ext_vector_type(2))) unsigned short u16x2;
typedef __attribute__((ext_vector_type(8))) short bf16x8;
typedef __attribute__((ext_vector_type(8))) unsigned short u16x8;
typedef __attribute__((ext_vector_type(4))) float f32x4;

__device__ __forceinline__ float bits2f(u16 u){ return __uint_as_float(((unsigned)u) << 16); }
__device__ __forceinline__ u16 f2bf(float f){
  bf16 h = __float2bfloat16(f);
  return *(u16*)&h;
}

// ---- K0: fragment-major operand layouts + b2 (b2 branch compacted) ---------
__global__ __launch_bounds__(256) void k0_prep(const float* __restrict__ C,
                                               const float* __restrict__ W,
                                               u16* __restrict__ CbP, u16* __restrict__ CtP,
                                               float* __restrict__ b2v, u16* __restrict__ WbP){
  const int t = threadIdx.x;
  const int bid = blockIdx.x;
  if (bid < 32){
    const int m = bid*8 + (t >> 5);
    const int pl = t & 31;
    float s = 0.f;
    for (int it = 0; it < 18; ++it){
      const int p = pl + it*32;
      float vr = bits2f(f2bf(C[(size_t)m*P_ + p]));
      s += vr*vr;
    }
    #pragma unroll
    for (int off = 16; off >= 1; off >>= 1) s += __shfl_xor(s, off);
    if (pl == 0) b2v[m] = s;
  } else if (bid < 32 + 72){
    const int u = (bid - 32)*256 + t;
    const int f = u >> 6, lane = u & 63;
    const int g = lane >> 4, lr = lane & 15;
    const int k = f % 18, fj = f / 18;
    const int j = fj & 3, wvq = fj >> 2;
    const int m = wvq*64 + j*16 + lr;
    const int idx = k*4 + g;
    const int o = idx & 7, rr = idx >> 3;
    u16x8 o8;
    #pragma unroll
    for (int c = 0; c < 8; ++c) o8[c] = f2bf(C[(size_t)m*P_ + (o*8 + c)*9 + rr]);
    *(u16x8*)&CbP[(size_t)u*8] = o8;
  } else if (bid < 32 + 144){
    const int u = (bid - 32 - 72)*256 + t;
    const int f = u >> 6, lane = u & 63;
    const int g = lane >> 4, lr = lane & 15;
    const int mc = f & 7, fj = f >> 3;
    const int j = fj % 9, q = fj / 9;
    const int p = q*144 + j*16 + lr;
    const int m = mc*32 + g*8;
    u16x8 o8;
    #pragma unroll
    for (int c = 0; c < 8; ++c) o8[c] = f2bf(C[(size_t)(m + c)*P_ + p]);
    *(u16x8*)&CtP[(size_t)u*8] = o8;
  } else {
    const int u = (bid - 32 - 144)*256 + t;
    const int f = u >> 6, lane = u & 63;
    const int g = lane >> 4, lr = lane & 15;
    const int k = f % 18, fi = f / 18;
    const int i = fi & 3, wn = fi >> 2;
    const int co = wn*64 + i*16 + lr;
    const int q = k*32 + g*8;
    u16x8 o8;
    #pragma unroll
    for (int c = 0; c < 8; ++c) o8[c] = f2bf(W[(size_t)co*P_ + q + c]);
    *(u16x8*)&WbP[(size_t)u*8] = o8;
  }
}

// ---- K123: fused unfold+assign+transform. 512 threads, 8 waves. ------------
// wv = ih*4+mq. XCD-aware block swizzle. Softmax without max-shift
// (logits <= 0, bounded below by ~-38: exp in [3e-17, 1] -- safe in f32).
__global__ __launch_bounds__(512, 4) void k123(const float* __restrict__ x,
    const u16* __restrict__ CbP, const u16* __restrict__ CtP,
    const float* __restrict__ b2v, const float* __restrict__ temp_p,
    u16* __restrict__ F){
  __shared__ __align__(16) char lds[76288];
  u16*   xt2 = (u16*)lds;                 // 256 spat x 72 u16 = 36864 B
  char*  Bz  = lds + 36864;               // 37888 B overlay: Sl / Fl
  u16*   Sl  = (u16*)Bz;                  // 64 x 264 u16 = 33792 B
  u16*   Fl  = (u16*)Bz;                  // 64 x 296 u16 = 37888 B
  float* a2l = (float*)(lds + 74752);     // 2 x 64 f (partials by ih)
  float* red = (float*)(lds + 75264);     // 256 f

  const int t = threadIdx.x;
  const int lane = t & 63;
  const int wv = t >> 6;                  // 0..7
  const int ih = wv >> 2;                 // row half
  const int mq = wv & 3;                  // m/p quarter
  const int g  = lane >> 4;
  const int lr = lane & 15;
  const int blk_raw = blockIdx.x;
  const int blk = (blk_raw & 7) * 196 + (blk_raw >> 3);   // XCD-chunked
  const int n0 = blk * 64;
  const int b  = n0 / L_;
  const int l0 = n0 - b * L_;
  const int h0 = l0 / 56;
  const float temp = *temp_p;

  // ---- stage x window transposed (channel-pair vectorized writes) ----
  const float* xb = x + (size_t)b * CIN * L_;
  {
    const int wc = t & 63;
    const int ix = wc - 1;
    const bool okx = (unsigned)ix < 56u;
    #pragma unroll 4
    for (int iter = 0; iter < 16; ++iter){
      const int idx = (t >> 6) + iter*8;   // 0..127 (channel-pair, ry)
      const int cp  = idx & 31;            // channel pair
      const int ry  = idx >> 5;            // 0..3
      const int c0  = cp*2;
      const int iy = h0 - 1 + ry;
      float v0 = 0.f, v1 = 0.f;
      if ((unsigned)iy < 56u && okx){
        v0 = xb[(size_t)c0*L_ + iy*56 + ix];
        v1 = xb[(size_t)(c0+1)*L_ + iy*56 + ix];
      }
      const int spat = ry*64 + wc;
      u16x2 o = { f2bf(v0), f2bf(v1) };
      *(u16x2*)&xt2[spat*72 + (((c0>>3) + 2*spat) & 7)*8 + (c0 & 7)] = o;
    }
  }
  __syncthreads();

  // ---- a2 partials: row = mq*16+lr; ih splits the 18 z-steps ----
  {
    const int l_  = l0 + mq*16 + lr;
    const int hwB = (l_/56 - h0)*64 + (l_ - (l_/56)*56);
    float s2 = 0.f;
    #pragma unroll
    for (int z = 0; z < 9; ++z){
      const int uu = (ih*9 + z)*4 + g;
      const int rr = uu >> 3, o = uu & 7;
      const int di = (rr >= 3) + (rr >= 6);
      const int spat = hwB + di*64 + (rr - di*3);
      u16x8 v8 = *(const u16x8*)&xt2[spat*72 + ((o + 2*spat) & 7)*8];
      #pragma unroll
      for (int c = 0; c < 8; ++c){
        const float vr = bits2f(v8[c]);
        s2 = fmaf(vr, vr, s2);
      }
    }
    s2 += __shfl_xor(s2, 16);
    s2 += __shfl_xor(s2, 32);
    if (g == 0) a2l[ih*64 + mq*16 + lr] = s2;
  }
  __syncthreads();               // a2l visible

  // ================= phase 1: G = A * Cb^T (no barriers) =================
  int hw2[2];
  #pragma unroll
  for (int i = 0; i < 2; ++i){
    const int li = l0 + ih*32 + i*16 + lr;
    const int hi = li / 56;
    hw2[i] = (hi - h0)*64 + (li - hi*56);
  }

  f32x4 acc[2][4];
  #pragma unroll
  for (int i = 0; i < 2; ++i)
    #pragma unroll
    for (int j = 0; j < 4; ++j) acc[i][j] = (f32x4){0.f,0.f,0.f,0.f};

  bf16x8 bbc[4], bbn[4];
  #pragma unroll
  for (int j = 0; j < 4; ++j)
    bbc[j] = *(const bf16x8*)(CbP + (((size_t)(mq*4 + j)*18 + 0)*64 + lane)*8);

  #pragma unroll
  for (int kk = 0; kk < 18; ++kk){
    const int idx = kk*4 + g;
    const int rr = idx >> 3, o = idx & 7;
    const int di = (rr >= 3) + (rr >= 6);
    const int doff = di*64 + (rr - di*3);
    bf16x8 af[2];
    #pragma unroll
    for (int i = 0; i < 2; ++i){
      const int spat = hw2[i] + doff;
      af[i] = *(const bf16x8*)&xt2[spat*72 + ((o + 2*spat) & 7)*8];
    }
    if (kk + 1 < 18){
      #pragma unroll
      for (int j = 0; j < 4; ++j)
        bbn[j] = *(const bf16x8*)(CbP + (((size_t)(mq*4 + j)*18 + (kk+1))*64 + lane)*8);
    }
    #pragma unroll
    for (int i = 0; i < 2; ++i)
      #pragma unroll
      for (int j = 0; j < 4; ++j)
        acc[i][j] = __builtin_amdgcn_mfma_f32_16x16x32_bf16(af[i], bbc[j], acc[i][j], 0, 0, 0);
    if (kk + 1 < 18){
      #pragma unroll
      for (int j = 0; j < 4; ++j) bbc[j] = bbn[j];
    }
  }

  // ---- softmax over all 256 m, WITHOUT max-shift (logits <= 0) ----
  float a2r[2][4], b2r[4];
  #pragma unroll
  for (int i = 0; i < 2; ++i)
    #pragma unroll
    for (int r = 0; r < 4; ++r){
      const int row = ih*32 + i*16 + g*4 + r;
      a2r[i][r] = a2l[row] + a2l[64 + row];
    }
  #pragma unroll
  for (int j = 0; j < 4; ++j) b2r[j] = b2v[mq*64 + j*16 + lr];

  float rsum[2][4];
  #pragma unroll
  for (int i = 0; i < 2; ++i)
    #pragma unroll
    for (int r = 0; r < 4; ++r) rsum[i][r] = 0.f;

  #pragma unroll
  for (int i = 0; i < 2; ++i)
    #pragma unroll
    for (int j = 0; j < 4; ++j)
      #pragma unroll
      for (int r = 0; r < 4; ++r){
        float d2 = fmaxf(a2r[i][r] + b2r[j] - 2.f*acc[i][j][r], 1e-12f);
        float pe = __expf(-temp * sqrtf(d2));
        acc[i][j][r] = pe;
        rsum[i][r] += pe;
      }
  #pragma unroll
  for (int i = 0; i < 2; ++i)
    #pragma unroll
    for (int r = 0; r < 4; ++r){
      float v = rsum[i][r];
      v += __shfl_xor(v, 1);
      v += __shfl_xor(v, 2);
      v += __shfl_xor(v, 4);
      v += __shfl_xor(v, 8);
      rsum[i][r] = v;
    }
  if (lr == 0){
    #pragma unroll
    for (int i = 0; i < 2; ++i)
      #pragma unroll
      for (int r = 0; r < 4; ++r)
        red[mq*64 + ih*32 + i*16 + g*4 + r] = rsum[i][r];
  }
  __syncthreads();
  #pragma unroll
  for (int i = 0; i < 2; ++i)
    #pragma unroll
    for (int r = 0; r < 4; ++r){
      const int row = ih*32 + i*16 + g*4 + r;
      const float invr = 1.f / (red[row] + red[64+row] + red[128+row] + red[192+row]);
      #pragma unroll
      for (int j = 0; j < 4; ++j)
        Sl[(size_t)row*264 + mq*64 + j*16 + lr] = f2bf(acc[i][j][r] * invr);
    }
  __syncthreads();                 // Sl visible

  // ========== phase 2: T = Sl * Ct (no barriers, batch frag loads) ==========
  f32x4 acc2[2][9];
  #pragma unroll
  for (int i = 0; i < 2; ++i)
    #pragma unroll
    for (int j = 0; j < 9; ++j) acc2[i][j] = (f32x4){0.f,0.f,0.f,0.f};

  for (int mc = 0; mc < 8; ++mc){
    bf16x8 af2[2], bb2[9];
    #pragma unroll
    for (int i = 0; i < 2; ++i)
      af2[i] = *(const bf16x8*)&Sl[(size_t)(ih*32 + i*16 + lr)*264 + mc*32 + g*8];
    #pragma unroll
    for (int j = 0; j < 9; ++j)
      bb2[j] = *(const bf16x8*)(CtP + (((size_t)(mq*9 + j)*8 + mc)*64 + lane)*8);
    #pragma unroll
    for (int j = 0; j < 9; ++j)
      #pragma unroll
      for (int i = 0; i < 2; ++i)
        acc2[i][j] = __builtin_amdgcn_mfma_f32_16x16x32_bf16(af2[i], bb2[j], acc2[i][j], 0, 0, 0);
  }

  // ---- F write: two 288-p halves; skip gather via magic-div (chain-free) ---
  const float inv = 1.f / (temp + 1.f);
  const float tscale = temp * inv;
  #pragma unroll
  for (int hh = 0; hh < 2; ++hh){
    __syncthreads();               // Fl region free
    if ((mq >> 1) == hh){
      const int pbase = (mq & 1) * 144;
      #pragma unroll
      for (int i = 0; i < 2; ++i)
        #pragma unroll
        for (int j = 0; j < 9; ++j)
          #pragma unroll
          for (int r = 0; r < 4; ++r)
            Fl[(ih*32 + i*16 + g*4 + r)*296 + pbase + j*16 + lr] = f2bf(acc2[i][j][r] * tscale);
    }
    __syncthreads();
    #pragma unroll
    for (int e = 0; e < 5; ++e){
      if (e == 4 && t >= 256) break;       // 2304 = 4*512 + 256
      const int v = t + e*512;
      const int row = v / 36, col = (v - row*36) * 8;
      u16x8 tv = *(const u16x8*)&Fl[row*296 + col];
      const int p0 = hh*288 + col;
      const int l2 = l0 + row;
      const int h2 = l2 / 56;
      const int hb2 = (h2 - h0)*64 + (l2 - h2*56);
      u16x8 o;
      #pragma unroll
      for (int c2 = 0; c2 < 8; ++c2){
        const int p  = p0 + c2;
        const int ch = (p * 7282) >> 16;   // exact p/9 for p < 3640*9
        const int rr = p - ch*9;
        const int di = (rr >= 3) + (rr >= 6);
        const int spat = hb2 + di*64 + (rr - di*3);
        const u16 av_ = xt2[spat*72 + (((ch>>3) + 2*spat) & 7)*8 + (ch & 7)];
        o[c2] = f2bf(bits2f(tv[c2]) + bits2f(av_) * inv);
      }
      *(u16x8*)(F + (size_t)(n0 + row)*P_ + hh*288 + col) = o;
    }
  }
}

// ---- K4: MFMA GEMM out = WbP * F (+bias). Double-buffered F staging. -------
__global__ __launch_bounds__(256) void k4_conv(const u16* __restrict__ F,
    const u16* __restrict__ WbP, const float* __restrict__ bias,
    float* __restrict__ out){
  __shared__ short Fl[2][128*40];   // 2 x 10 KB
  const int t = threadIdx.x;
  const int lane = t & 63;
  const int w = t >> 6;
  const int wn = w >> 1;
  const int ws = w & 1;
  const int g  = lane >> 4;
  const int lr = lane & 15;
  const int b  = blockIdx.y;
  const int s0 = blockIdx.x * 128;
  const u16* Fb = F + (size_t)b * ((size_t)P_ * L_);

  const int ql  = t & 31;
  const int sch = t >> 5;                 // 0..7
  const int sb0 = s0 + sch*8;
  const int sb1 = s0 + (sch + 8)*8;
  const int sc0 = (sb0 < L_ - 8) ? sb0 : (L_ - 8);
  const int sc1 = (sb1 < L_ - 8) ? sb1 : (L_ - 8);
  const int r00 = sb0 % 56;
  const int r01 = sb1 % 56;

  f32x4 acc[4][4];
  #pragma unroll
  for (int i = 0; i < 4; ++i)
    #pragma unroll
    for (int j = 0; j < 4; ++j) acc[i][j] = (f32x4){0.f,0.f,0.f,0.f};

  u16x8 vv0, vv1;
  {
    vv0 = *(const u16x8*)(Fb + (size_t)(0*32 + ql)*L_ + sc0);
    vv1 = *(const u16x8*)(Fb + (size_t)(0*32 + ql)*L_ + sc1);
    const int q = ql;
    const int q3 = q/3;
    const bool kx0 = (q - q3*3) == 0;
    const bool ky0 = (q3 % 3) == 0;
    #pragma unroll
    for (int u = 0; u < 8; ++u){
      const bool m0a = ky0 && (sb0 + u) < 56;
      const bool m1a = kx0 && ((r00 + u) == 0 || (r00 + u) == 56);
      Fl[0][(sch*8 + u)*40 + ql] = (m0a || m1a) ? (short)0 : (short)vv0[u];
      const bool m0b = ky0 && (sb1 + u) < 56;
      const bool m1b = kx0 && ((r01 + u) == 0 || (r01 + u) == 56);
      Fl[0][((sch+8)*8 + u)*40 + ql] = (m0b || m1b) ? (short)0 : (short)vv1[u];
    }
    vv0 = *(const u16x8*)(Fb + (size_t)(1*32 + ql)*L_ + sc0);
    vv1 = *(const u16x8*)(Fb + (size_t)(1*32 + ql)*L_ + sc1);
  }
  __syncthreads();

  for (int step = 0; step < 18; ++step){
    const short* cur = Fl[step & 1];
    bf16x8 af[4], bb[4];
    #pragma unroll
    for (int i = 0; i < 4; ++i)
      af[i] = *(const bf16x8*)(WbP + (((size_t)(wn*4 + i)*18 + step)*64 + lane)*8);
    #pragma unroll
    for (int j = 0; j < 4; ++j)
      bb[j] = *(const bf16x8*)&cur[(ws*64 + j*16 + lr)*40 + g*8];
    #pragma unroll
    for (int i = 0; i < 4; ++i)
      #pragma unroll
      for (int j = 0; j < 4; ++j)
        acc[i][j] = __builtin_amdgcn_mfma_f32_16x16x32_bf16(af[i], bb[j], acc[i][j], 0, 0, 0);

    if (step + 1 < 18){
      short* nxt = Fl[(step + 1) & 1];
      const int q = (step + 1)*32 + ql;
      const int q3 = q/3;
      const bool kx0 = (q - q3*3) == 0;
      const bool ky0 = (q3 % 3) == 0;
      #pragma unroll
      for (int u = 0; u < 8; ++u){
        const bool m0a = ky0 && (sb0 + u) < 56;
        const bool m1a = kx0 && ((r00 + u) == 0 || (r00 + u) == 56);
        nxt[(sch*8 + u)*40 + ql] = (m0a || m1a) ? (short)0 : (short)vv0[u];
        const bool m0b = ky0 && (sb1 + u) < 56;
        const bool m1b = kx0 && ((r01 + u) == 0 || (r01 + u) == 56);
        nxt[((sch+8)*8 + u)*40 + ql] = (m0b || m1b) ? (short)0 : (short)vv1[u];
      }
      if (step + 2 < 18){
        vv0 = *(const u16x8*)(Fb + (size_t)((step+2)*32 + ql)*L_ + sc0);
        vv1 = *(const u16x8*)(Fb + (size_t)((step+2)*32 + ql)*L_ + sc1);
      }
    }
    __syncthreads();
  }

  #pragma unroll
  for (int i = 0; i < 4; ++i)
    #pragma unroll
    for (int r = 0; r < 4; ++r){
      const int co = wn*64 + i*16 + g*4 + r;
      const float bv = bias[co];
      #pragma unroll
      for (int j = 0; j < 4; ++j){
        const int s = s0 + ws*64 + j*16 + lr;
        if (s < L_) out[((size_t)b*COUT + co)*L_ + s] = acc[i][j][r] + bv;
      }
    }
}

extern "C" void kernel_launch(void* const* d_in, const int* in_sizes, int n_in,
                              void* d_out, int out_size, void* d_ws, size_t ws_size,
                              hipStream_t stream){
  const float* x      = (const float*)d_in[0];
  const float* weight = (const float*)d_in[1];
  const float* bias   = (const float*)d_in[2];
  const float* cc     = (const float*)d_in[3];
  const float* temp_p = (const float*)d_in[4];
  float* out = (float*)d_out;

  char* ws = (char*)d_ws;
  u16*   F   = (u16*)(ws);                 // 115,605,504 B (standard [n][p])
  float* b2v = (float*)(ws + 115605504);   //       1,024 B
  u16*   CbP = (u16*)(ws + 115606528);     //     294,912 B
  u16*   CtP = (u16*)(ws + 115901440);     //     294,912 B
  u16*   WbP = (u16*)(ws + 116196352);     //     147,456 B

  k0_prep <<<212,          256, 0, stream>>>(cc, weight, CbP, CtP, b2v, WbP);
  k123    <<<N_/64,        512, 0, stream>>>(x, CbP, CtP, b2v, temp_p, F);
  k4_conv <<<dim3(25, B_), 256, 0, stream>>>(F, WbP, bias, out);
}